// Round 13
// baseline (3600.520 us; speedup 1.0000x reference)
//
#include <hip/hip_runtime.h>
#include <hip/hip_bf16.h>
#include <math.h>

// ---------------- problem constants ----------------
#define BATCH 32
#define NTOK  197
#define NPATCH 196
#define DMODEL 768
#define NLAYER 12
#define NHEAD 12
#define HDIM  64
#define ROWS  (BATCH*NTOK)     // 6304
#define CROWS (BATCH*NPATCH)   // 6272
#define DFF   3072
#define DQKV  2304
#define DOUT  512
#define NBH   (BATCH*NHEAD)

// per-layer weight slab offsets (bf16 elems)
#define WOFF_IN   ((size_t)0)
#define WOFF_OUT  ((size_t)(DQKV*DMODEL))
#define WOFF_FC   (WOFF_OUT + (size_t)(DMODEL*DMODEL))
#define WOFF_CP   (WOFF_FC + (size_t)(DFF*DMODEL))
#define WTOT      (WOFF_CP + (size_t)(DMODEL*DFF))      // 7,077,888 bf16

// workspace layout (float units)
#define WS_H    ((size_t)0)
#define WS_QKVB (WS_H + (size_t)ROWS*DMODEL)
#define WS_GB   (WS_QKVB + (size_t)ROWS*DQKV/2)
#define WS_TB   (WS_GB + (size_t)ROWS*DFF/2)
#define WS_WL   (WS_TB + (size_t)ROWS*DMODEL/2)          // 2 slabs of WTOT bf16 = WTOT floats
#define WS_PTS  (WS_WL + WTOT)
#define WS_ADD  (WS_PTS + (size_t)DOUT*DMODEL/2)

typedef unsigned short ushort_t;
typedef __attribute__((ext_vector_type(8))) short bf16x8;
typedef __attribute__((ext_vector_type(4))) float f32x4;

__device__ inline ushort_t bf16rn(float x) {
    uint32_t u = __builtin_bit_cast(uint32_t, x);
    uint32_t r = (u + 0x7FFFu + ((u >> 16) & 1u)) >> 16;
    return (ushort_t)r;
}

#define GLL(src, dst) __builtin_amdgcn_global_load_lds( \
    (const __attribute__((address_space(1))) void*)(src), \
    (__attribute__((address_space(3))) void*)(dst), 16, 0, 0)

// ---------------- small kernels ----------------

__global__ void im2col_bf16_k(const float* __restrict__ x, ushort_t* __restrict__ out) {
    int idx = blockIdx.x * 256 + threadIdx.x;
    if (idx >= CROWS * DMODEL / 4) return;
    int r  = idx / (DMODEL / 4);
    int k4 = (idx - r * (DMODEL / 4)) * 4;
    int b = r / NPATCH, p = r - b * NPATCH;
    int py = p / 14, px = p - py * 14;
    int c = k4 >> 8, rem = k4 & 255, i = rem >> 4, j = rem & 15;
    const float* xp = x + (((size_t)(b * 3 + c) * 224) + py * 16 + i) * 224 + px * 16 + j;
    float4 v = *(const float4*)xp;
    ushort4 hv = {bf16rn(v.x), bf16rn(v.y), bf16rn(v.z), bf16rn(v.w)};
    *(ushort4*)(out + (size_t)r * DMODEL + k4) = hv;
}

__global__ void cvt_w_k(const float* __restrict__ W, ushort_t* __restrict__ out, int NK) {
    int idx = (blockIdx.x * 256 + threadIdx.x) * 4;
    if (idx >= NK) return;
    float4 v = *(const float4*)(W + idx);
    ushort4 hv = {bf16rn(v.x), bf16rn(v.y), bf16rn(v.z), bf16rn(v.w)};
    *(ushort4*)(out + idx) = hv;
}

// one layer's 4 weight mats -> wl slab (used once, for layer 0)
__global__ void cvt_layer_k(const float* __restrict__ inW, const float* __restrict__ outW,
                            const float* __restrict__ fcW, const float* __restrict__ cpW,
                            ushort_t* __restrict__ wl) {
    size_t idx = ((size_t)blockIdx.x * 256 + threadIdx.x) * 4;
    if (idx >= WTOT) return;
    const float* src; size_t off;
    if (idx < WOFF_OUT)      { src = inW;  off = idx; }
    else if (idx < WOFF_FC)  { src = outW; off = idx - WOFF_OUT; }
    else if (idx < WOFF_CP)  { src = fcW;  off = idx - WOFF_FC; }
    else                     { src = cpW;  off = idx - WOFF_CP; }
    float4 v = *(const float4*)(src + off);
    ushort4 hv = {bf16rn(v.x), bf16rn(v.y), bf16rn(v.z), bf16rn(v.w)};
    *(ushort4*)(wl + idx) = hv;
}

__global__ void cvt_pT_k(const float* __restrict__ proj, ushort_t* __restrict__ out) {
    int idx = blockIdx.x * 256 + threadIdx.x;
    if (idx >= DOUT * DMODEL) return;
    int n = idx / DMODEL, k = idx - n * DMODEL;
    out[(size_t)n * DMODEL + k] = bf16rn(proj[(size_t)k * DOUT + n]);
}

__global__ void gauss_k(float* __restrict__ add) {
    int idx = blockIdx.x * 256 + threadIdx.x;
    if (idx >= NTOK * NTOK) return;
    int i = idx / NTOK, j = idx - i * NTOK;
    float v = 0.f;
    if (i > 0 && j > 0) {
        int p = i - 1, q = j - 1;
        int di = q / 14 - p / 14;
        int dj = q % 14 - p % 14;
        v = expf(-(float)(di * di + dj * dj) * 0.02f);
    }
    add[idx] = v;
}

// fused: embed (cls/conv + pos) then ln_pre, writes f32 h
__global__ __launch_bounds__(256) void embed_lnpre_k(const float* __restrict__ conv,
                                                     const float* __restrict__ cls,
                                                     const float* __restrict__ pos,
                                                     const float* __restrict__ w,
                                                     const float* __restrict__ b,
                                                     float* __restrict__ h) {
    int row = blockIdx.x, tid = threadIdx.x;
    int bb = row / NTOK, tok = row - bb * NTOK;
    float e[3];
    #pragma unroll
    for (int c = 0; c < 3; ++c) {
        int d = tid + c * 256;
        float v = (tok == 0) ? cls[d] : conv[((size_t)(bb * NPATCH + tok - 1)) * DMODEL + d];
        e[c] = v + pos[(size_t)tok * DMODEL + d];
    }
    float s = e[0] + e[1] + e[2];
    float s2 = e[0]*e[0] + e[1]*e[1] + e[2]*e[2];
    for (int o = 32; o > 0; o >>= 1) { s += __shfl_down(s, o); s2 += __shfl_down(s2, o); }
    __shared__ float red[8];
    int wid = tid >> 6;
    if ((tid & 63) == 0) { red[wid] = s; red[4 + wid] = s2; }
    __syncthreads();
    s  = red[0] + red[1] + red[2] + red[3];
    s2 = red[4] + red[5] + red[6] + red[7];
    float mean = s * (1.0f / 768.0f);
    float var  = s2 * (1.0f / 768.0f) - mean * mean;
    float rinv = rsqrtf(var + 1e-5f);
    float* o_ = h + (size_t)row * DMODEL;
    #pragma unroll
    for (int c = 0; c < 3; ++c) {
        int d = tid + c * 256;
        o_[d] = (e[c] - mean) * rinv * w[d] + b[d];
    }
}

__global__ __launch_bounds__(256) void ln768_bf16_k(const float* __restrict__ in, ushort_t* __restrict__ out,
                                                    const float* __restrict__ w, const float* __restrict__ b) {
    int row = blockIdx.x, tid = threadIdx.x;
    const float* x = in + (size_t)row * DMODEL;
    float v0 = x[tid], v1 = x[tid + 256], v2 = x[tid + 512];
    float s = v0 + v1 + v2;
    float s2 = v0 * v0 + v1 * v1 + v2 * v2;
    for (int o = 32; o > 0; o >>= 1) { s += __shfl_down(s, o); s2 += __shfl_down(s2, o); }
    __shared__ float red[8];
    int wid = tid >> 6;
    if ((tid & 63) == 0) { red[wid] = s; red[4 + wid] = s2; }
    __syncthreads();
    s  = red[0] + red[1] + red[2] + red[3];
    s2 = red[4] + red[5] + red[6] + red[7];
    float mean = s * (1.0f / 768.0f);
    float var  = s2 * (1.0f / 768.0f) - mean * mean;
    float rinv = rsqrtf(var + 1e-5f);
    ushort_t* o_ = out + (size_t)row * DMODEL;
    o_[tid]       = bf16rn((v0 - mean) * rinv * w[tid]       + b[tid]);
    o_[tid + 256] = bf16rn((v1 - mean) * rinv * w[tid + 256] + b[tid + 256]);
    o_[tid + 512] = bf16rn((v2 - mean) * rinv * w[tid + 512] + b[tid + 512]);
}

// ---------------- single-barrier DEPTH=3 MFMA GEMM + XCD swizzle + optional fused weight-cvt --------
// Normal blocks (lin < nm*nn*nz): bijective XCD remap groups the nn*nz blocks sharing one
// A-panel (m) onto one XCD's L2 (T1/m204).  Extra blocks (lin >= normal): stream-convert the
// NEXT layer's f32 weights into cdst (double-buffered wl) — removes 12 serial cvt launches.
// mode 0: C = r + bias ; mode 1: OS = bf16(gelu(r+bias)) ; mode 3: atomicAdd(C, ...) ; mode 4: OS = bf16(r+bias)
template<int DEPTH>
__global__ __launch_bounds__(256) void gemm_mfma_k(
    const ushort_t* __restrict__ A, const ushort_t* __restrict__ W,
    const float* __restrict__ bias, float* __restrict__ C, ushort_t* __restrict__ OS,
    int M, int N, int K, int mode,
    const float* __restrict__ c0, const float* __restrict__ c1,
    const float* __restrict__ c2, const float* __restrict__ c3, ushort_t* __restrict__ cdst)
{
    __shared__ ushort_t As[DEPTH][128][32];
    __shared__ ushort_t Bs[DEPTH][128][32];
    int tid = threadIdx.x;

    int nm = (M + 127) >> 7;
    int nn = N >> 7;
    int nz = gridDim.z;
    int normal = nm * nn * nz;
    int lin = blockIdx.x + gridDim.x * (blockIdx.y + gridDim.y * blockIdx.z);
    int nwg = gridDim.x * gridDim.y * gridDim.z;

    if (lin >= normal) {
        // fused next-layer weight conversion (whole block diverges; no barriers used)
        int cvtb = nwg - normal;
        size_t i = (size_t)(lin - normal) * 256 + tid;
        size_t stride = (size_t)cvtb * 256;
        for (; i < WTOT / 4; i += stride) {
            size_t idx = i * 4;
            const float* src; size_t off;
            if (idx < WOFF_OUT)      { src = c0; off = idx; }
            else if (idx < WOFF_FC)  { src = c1; off = idx - WOFF_OUT; }
            else if (idx < WOFF_CP)  { src = c2; off = idx - WOFF_FC; }
            else                     { src = c3; off = idx - WOFF_CP; }
            float4 v = *(const float4*)(src + off);
            ushort4 hv = {bf16rn(v.x), bf16rn(v.y), bf16rn(v.z), bf16rn(v.w)};
            *(ushort4*)(cdst + idx) = hv;
        }
        return;
    }

    // bijective XCD swizzle (xcd = lin%8 hardware round-robin assumption)
    int q = normal >> 3, rr = normal & 7;
    int xcd = lin & 7, kk = lin >> 3;
    int w = (xcd < rr) ? (xcd * (q + 1) + kk) : (rr * (q + 1) + (xcd - rr) * q + kk);
    int pm = nn * nz;
    int mb = w / pm;
    int rest = w - mb * pm;
    int nb = rest / nz;
    int zb = rest - nb * nz;
    int m0 = mb * 128, n0 = nb * 128;

    int lane = tid & 63;
    int wave = tid >> 6;
    int wm = wave >> 1, wn = wave & 1;

    int klen = K / nz;
    int kbeg = zb * klen;
    int nt = klen / 32;

    f32x4 acc[4][4];
    #pragma unroll
    for (int i = 0; i < 4; ++i)
        #pragma unroll
        for (int j = 0; j < 4; ++j)
            acc[i][j] = (f32x4){0.f, 0.f, 0.f, 0.f};

    int srow = tid >> 2;
    int skq  = (((tid & 3) ^ ((tid >> 3) & 3)) * 8);      // pre-swizzled source slot
    int ar0 = m0 + srow;      if (ar0 > M - 1) ar0 = M - 1;
    int ar1 = m0 + srow + 64; if (ar1 > M - 1) ar1 = M - 1;
    const ushort_t* Ap0 = A + (size_t)ar0 * K + kbeg + skq;
    const ushort_t* Ap1 = A + (size_t)ar1 * K + kbeg + skq;
    const ushort_t* Wp0 = W + (size_t)(n0 + srow) * K + kbeg + skq;
    const ushort_t* Wp1 = W + (size_t)(n0 + srow + 64) * K + kbeg + skq;
    char* ldsA = (char*)As + tid * 16;
    char* ldsB = (char*)Bs + tid * 16;

    int fr = lane & 15, fq = lane >> 4;
    int rsl = (fq ^ ((fr >> 1) & 3)) * 8;                 // swizzled read slot

    #define STAGE(buf_, ko_) do {                         \
        GLL(Ap0 + (ko_), ldsA + (buf_) * 8192);           \
        GLL(Ap1 + (ko_), ldsA + (buf_) * 8192 + 4096);    \
        GLL(Wp0 + (ko_), ldsB + (buf_) * 8192);           \
        GLL(Wp1 + (ko_), ldsB + (buf_) * 8192 + 4096);    \
    } while (0)

    STAGE(0, 0);
    if (nt > 1) STAGE(1, 32);

    int cur = 0, pre = (DEPTH - 1) % DEPTH;
    for (int t = 0; t < nt; ++t) {
        if (t + 1 < nt) asm volatile("s_waitcnt vmcnt(4)" ::: "memory");
        else            asm volatile("s_waitcnt vmcnt(0)" ::: "memory");
        __builtin_amdgcn_s_barrier();
        if (t + DEPTH - 1 < nt) STAGE(pre, (size_t)(t + DEPTH - 1) * 32);
        bf16x8 a[4], b[4];
        #pragma unroll
        for (int fm = 0; fm < 4; ++fm)
            a[fm] = *(const bf16x8*)&As[cur][wm * 64 + fm * 16 + fr][rsl];
        #pragma unroll
        for (int fn = 0; fn < 4; ++fn)
            b[fn] = *(const bf16x8*)&Bs[cur][wn * 64 + fn * 16 + fr][rsl];
        #pragma unroll
        for (int fm = 0; fm < 4; ++fm)
            #pragma unroll
            for (int fn = 0; fn < 4; ++fn)
                acc[fm][fn] = __builtin_amdgcn_mfma_f32_16x16x32_bf16(a[fm], b[fn], acc[fm][fn], 0, 0, 0);
        cur = (cur + 1 == DEPTH) ? 0 : cur + 1;
        pre = (pre + 1 == DEPTH) ? 0 : pre + 1;
    }
    #undef STAGE

    // epilogue: D col = lane&15 (fr), row = fq*4 + j
    #pragma unroll
    for (int fn = 0; fn < 4; ++fn) {
        int ccol = n0 + wn * 64 + fn * 16 + fr;
        float bv = bias ? bias[ccol] : 0.f;
        if (mode == 3 && zb != 0) bv = 0.f;
        #pragma unroll
        for (int fm = 0; fm < 4; ++fm) {
            int crow0 = m0 + wm * 64 + fm * 16 + fq * 4;
            #pragma unroll
            for (int j = 0; j < 4; ++j) {
                int row = crow0 + j;
                if (row < M) {
                    float v = acc[fm][fn][j] + bv;
                    if (mode == 0) {
                        C[(size_t)row * N + ccol] = v;
                    } else if (mode == 3) {
                        atomicAdd(&C[(size_t)row * N + ccol], v);
                    } else if (mode == 4) {
                        OS[(size_t)row * N + ccol] = bf16rn(v);
                    } else {
                        v = v / (1.0f + expf(-1.702f * v));
                        OS[(size_t)row * N + ccol] = bf16rn(v);
                    }
                }
            }
        }
    }
}

// ---------------- fused MFMA flash attention, swapped-QK^T, 8 waves, q-split ----------------
__global__ __launch_bounds__(512, 4) void attn_fused_k(
    const ushort_t* __restrict__ qkvb, ushort_t* __restrict__ out,
    const float* __restrict__ addition, int qoff)
{
    __shared__ ushort_t Ks[208][72];
    __shared__ ushort_t Vt[64][232];
    __shared__ ushort_t Pb[8][2][16][40];
    int tid = threadIdx.x;
    int bh = blockIdx.x;
    int b = bh / NHEAD, hh = bh - b * NHEAD;
    const ushort_t* base = qkvb + (size_t)b * NTOK * DQKV + hh * HDIM;

    int lane = tid & 63, wave = tid >> 6;
    int fr = lane & 15, fq = lane >> 4;
    int qt = blockIdx.y * 8 + wave;

    bf16x8 qf0, qf1;
    if (qt < 13) {
        int qrow = qt * 16 + fr; if (qrow > NTOK - 1) qrow = NTOK - 1;
        const ushort_t* qp = base + (size_t)qrow * DQKV + qoff + fq * 8;
        qf0 = *(const bf16x8*)qp;
        qf1 = *(const bf16x8*)(qp + 32);
    }

    {
        int tt = tid >> 4, dq = tid & 15;
        #pragma unroll
        for (int pass = 0; pass < 7; ++pass) {
            int t = pass * 32 + tt;
            if (t < 208) {
                ushort4 kv = {0, 0, 0, 0}, vv = {0, 0, 0, 0};
                if (t < NTOK) {
                    kv = *(const ushort4*)(base + (size_t)t * DQKV + DMODEL + dq * 4);
                    vv = *(const ushort4*)(base + (size_t)t * DQKV + 2 * DMODEL + dq * 4);
                }
                *(ushort4*)&Ks[t][dq * 4] = kv;
                Vt[dq * 4 + 0][t] = vv.x;
                Vt[dq * 4 + 1][t] = vv.y;
                Vt[dq * 4 + 2][t] = vv.z;
                Vt[dq * 4 + 3][t] = vv.w;
            }
        }
        for (int z = tid; z < 64 * 24; z += 512) Vt[z / 24][208 + z % 24] = 0;
    }
    __syncthreads();

    if (qt < 13) {
        int i0 = qt * 16;
        int irow = i0 + fr; if (irow > NTOK - 1) irow = NTOK - 1;

        f32x4 s[13];
        #pragma unroll
        for (int jt = 0; jt < 13; ++jt) {
            bf16x8 k0 = *(const bf16x8*)&Ks[jt * 16 + fr][fq * 8];
            bf16x8 k1 = *(const bf16x8*)&Ks[jt * 16 + fr][32 + fq * 8];
            f32x4 a = {0.f, 0.f, 0.f, 0.f};
            a = __builtin_amdgcn_mfma_f32_16x16x32_bf16(k0, qf0, a, 0, 0, 0);
            a = __builtin_amdgcn_mfma_f32_16x16x32_bf16(k1, qf1, a, 0, 0, 0);
            s[jt] = a;
        }

        float mx = -1e30f;
        #pragma unroll
        for (int jt = 0; jt < 13; ++jt) {
            int jb = jt * 16 + fq * 4;
            #pragma unroll
            for (int jj = 0; jj < 4; ++jj) {
                int j = jb + jj;
                float v = s[jt][jj] * 0.125f;
                if (addition) v += addition[irow * NTOK + (j < NTOK ? j : NTOK - 1)];
                if (j >= NTOK) v = -1e30f;
                s[jt][jj] = v;
                mx = fmaxf(mx, v);
            }
        }
        mx = fmaxf(mx, __shfl_xor(mx, 16));
        mx = fmaxf(mx, __shfl_xor(mx, 32));
        float sum = 0.f;
        #pragma unroll
        for (int jt = 0; jt < 13; ++jt)
            #pragma unroll
            for (int jj = 0; jj < 4; ++jj) {
                float e = __expf(s[jt][jj] - mx);
                s[jt][jj] = e;
                sum += e;
            }
        sum += __shfl_xor(sum, 16);
        sum += __shfl_xor(sum, 32);
        float inv = 1.0f / sum;

        f32x4 o4[4];
        #pragma unroll
        for (int dt = 0; dt < 4; ++dt) o4[dt] = (f32x4){0.f, 0.f, 0.f, 0.f};

        #define WRITE_P(st_, buf_) do {                                              \
            int jA = 2 * (st_), jB = jA + 1;                                         \
            ushort4 wa = {bf16rn(s[jA][0] * inv), bf16rn(s[jA][1] * inv),            \
                          bf16rn(s[jA][2] * inv), bf16rn(s[jA][3] * inv)};           \
            ushort4 wb = {0, 0, 0, 0};                                               \
            if (jB < 13) wb = (ushort4){bf16rn(s[jB][0] * inv), bf16rn(s[jB][1] * inv), \
                                        bf16rn(s[jB][2] * inv), bf16rn(s[jB][3] * inv)}; \
            *(ushort4*)&Pb[wave][buf_][fr][fq * 4] = wa;                             \
            *(ushort4*)&Pb[wave][buf_][fr][16 + fq * 4] = wb;                        \
        } while (0)

        WRITE_P(0, 0);
        for (int st = 0; st < 7; ++st) {
            asm volatile("s_waitcnt lgkmcnt(0)" ::: "memory");
            bf16x8 pa = *(const bf16x8*)&Pb[wave][st & 1][fr][fq * 8];
            bf16x8 vf0 = *(const bf16x8*)&Vt[0 * 16 + fr][st * 32 + fq * 8];
            bf16x8 vf1 = *(const bf16x8*)&Vt[1 * 16 + fr][st * 32 + fq * 8];
            bf16x8 vf2 = *(const bf16x8*)&Vt[2 * 16 + fr][st * 32 + fq * 8];
            bf16x8 vf3 = *(const bf16x8*)&Vt[3 * 16 + fr][st * 32 + fq * 8];
            if (st < 6) WRITE_P(st + 1, (st + 1) & 1);
            o4[0] = __builtin_amdgcn_mfma_f32_16x16x32_bf16(pa, vf0, o4[0], 0, 0, 0);
            o4[1] = __builtin_amdgcn_mfma_f32_16x16x32_bf16(pa, vf1, o4[1], 0, 0, 0);
            o4[2] = __builtin_amdgcn_mfma_f32_16x16x32_bf16(pa, vf2, o4[2], 0, 0, 0);
            o4[3] = __builtin_amdgcn_mfma_f32_16x16x32_bf16(pa, vf3, o4[3], 0, 0, 0);
        }
        #undef WRITE_P

        #pragma unroll
        for (int jj = 0; jj < 4; ++jj) {
            int ir = i0 + fq * 4 + jj;
            if (ir < NTOK) {
                ushort_t* op = out + ((size_t)(b * NTOK + ir)) * DMODEL + hh * HDIM + fr;
                #pragma unroll
                for (int dt = 0; dt < 4; ++dt)
                    op[dt * 16] = bf16rn(o4[dt][jj]);
            }
        }
    }
}

#define NOCVT nullptr, nullptr, nullptr, nullptr, nullptr

// ---------------- launch ----------------
extern "C" void kernel_launch(void* const* d_in, const int* in_sizes, int n_in,
                              void* d_out, int out_size, void* d_ws, size_t ws_size,
                              hipStream_t stream) {
    const float* x        = (const float*)d_in[0];
    const float* conv1_w  = (const float*)d_in[1];
    const float* cls      = (const float*)d_in[2];
    const float* pos      = (const float*)d_in[3];
    const float* ln_pre_w = (const float*)d_in[4];
    const float* ln_pre_b = (const float*)d_in[5];
    const float* in_proj_w  = (const float*)d_in[6];
    const float* in_proj_b  = (const float*)d_in[7];
    const float* out_proj_w = (const float*)d_in[8];
    const float* out_proj_b = (const float*)d_in[9];
    const float* ln1_w = (const float*)d_in[10];
    const float* ln1_b = (const float*)d_in[11];
    const float* ln2_w = (const float*)d_in[12];
    const float* ln2_b = (const float*)d_in[13];
    const float* fc_w  = (const float*)d_in[14];
    const float* fc_b  = (const float*)d_in[15];
    const float* cproj_w = (const float*)d_in[16];
    const float* cproj_b = (const float*)d_in[17];
    const float* ln_post_w = (const float*)d_in[18];
    const float* ln_post_b = (const float*)d_in[19];
    const float* proj = (const float*)d_in[20];
    float* out = (float*)d_out;

    float* ws   = (float*)d_ws;
    float* h    = ws + WS_H;
    float* ctmp = ws + WS_QKVB;                          // conv f32 tmp (aliases qkvb)
    ushort_t* qkvb = (ushort_t*)(ws + WS_QKVB);
    ushort_t* gb   = (ushort_t*)(ws + WS_GB);
    ushort_t* tb   = (ushort_t*)(ws + WS_TB);
    ushort_t* wl   = (ushort_t*)(ws + WS_WL);            // 2 slabs of WTOT bf16
    ushort_t* pTs  = (ushort_t*)(ws + WS_PTS);
    float* add  = ws + WS_ADD;

    // conv weights staged in gb region (free until layer-0 fc)
    ushort_t* convw = gb;

    im2col_bf16_k<<<(CROWS * DMODEL / 4 + 255) / 256, 256, 0, stream>>>(x, tb);
    cvt_w_k<<<(DMODEL * DMODEL / 4 + 255) / 256, 256, 0, stream>>>(conv1_w, convw, DMODEL * DMODEL);
    hipMemsetAsync(ctmp, 0, (size_t)CROWS * DMODEL * sizeof(float), stream);
    gemm_mfma_k<3><<<dim3(49, 6, 2), 256, 0, stream>>>(
        tb, convw, nullptr, ctmp, nullptr, CROWS, DMODEL, DMODEL, 3, NOCVT);
    embed_lnpre_k<<<ROWS, 256, 0, stream>>>(ctmp, cls, pos, ln_pre_w, ln_pre_b, h);
    gauss_k<<<(NTOK * NTOK + 255) / 256, 256, 0, stream>>>(add);
    cvt_pT_k<<<(DOUT * DMODEL + 255) / 256, 256, 0, stream>>>(proj, pTs);
    // layer-0 weights up front
    cvt_layer_k<<<(int)(WTOT / 4 / 256), 256, 0, stream>>>(in_proj_w, out_proj_w, fc_w, cproj_w, wl);

    const int GY = (ROWS + 127) / 128;  // 50
    for (int l = 0; l < NLAYER; ++l) {
        ushort_t* wlp = wl + (size_t)(l & 1) * WTOT;
        ln768_bf16_k<<<ROWS, 256, 0, stream>>>(h, tb, ln1_w + l * DMODEL, ln1_b + l * DMODEL);
        if (l + 1 < NLAYER) {
            // qkv GEMM + 100 trailing blocks converting layer (l+1) weights into the other slab
            int l2 = l + 1;
            gemm_mfma_k<3><<<dim3(GY, DQKV / 128 + 2), 256, 0, stream>>>(
                tb, wlp + WOFF_IN, in_proj_b + (size_t)l * DQKV, nullptr, qkvb, ROWS, DQKV, DMODEL, 4,
                in_proj_w + (size_t)l2 * DQKV * DMODEL, out_proj_w + (size_t)l2 * DMODEL * DMODEL,
                fc_w + (size_t)l2 * DFF * DMODEL, cproj_w + (size_t)l2 * DMODEL * DFF,
                wl + (size_t)(l2 & 1) * WTOT);
        } else {
            gemm_mfma_k<3><<<dim3(GY, DQKV / 128), 256, 0, stream>>>(
                tb, wlp + WOFF_IN, in_proj_b + (size_t)l * DQKV, nullptr, qkvb, ROWS, DQKV, DMODEL, 4, NOCVT);
        }
        bool nac = (l == NLAYER - 1);
        attn_fused_k<<<dim3(NBH, 2), 512, 0, stream>>>(qkvb, tb, nac ? add : nullptr, nac ? DMODEL : 0);
        gemm_mfma_k<3><<<dim3(GY, DMODEL / 128, 2), 256, 0, stream>>>(
            tb, wlp + WOFF_OUT, out_proj_b + (size_t)l * DMODEL, h, nullptr, ROWS, DMODEL, DMODEL, 3, NOCVT);
        ln768_bf16_k<<<ROWS, 256, 0, stream>>>(h, tb, ln2_w + l * DMODEL, ln2_b + l * DMODEL);
        gemm_mfma_k<3><<<dim3(GY, DFF / 128), 256, 0, stream>>>(
            tb, wlp + WOFF_FC, fc_b + (size_t)l * DFF, nullptr, gb, ROWS, DFF, DMODEL, 1, NOCVT);
        gemm_mfma_k<3><<<dim3(GY, DMODEL / 128, 2), 256, 0, stream>>>(
            gb, wlp + WOFF_CP, cproj_b + (size_t)l * DMODEL, h, nullptr, ROWS, DMODEL, DFF, 3, NOCVT);
    }

    ln768_bf16_k<<<ROWS, 256, 0, stream>>>(h, tb, ln_post_w, ln_post_b);
    hipMemsetAsync(out, 0, (size_t)out_size * sizeof(float), stream);
    gemm_mfma_k<3><<<dim3(GY, DOUT / 128, 2), 256, 0, stream>>>(
        tb, pTs, nullptr, out, nullptr, ROWS, DOUT, DMODEL, 3, NOCVT);
}

// Round 14
// 3589.230 us; speedup vs baseline: 1.0031x; 1.0031x over previous
//
#include <hip/hip_runtime.h>
#include <hip/hip_bf16.h>
#include <math.h>

// ---------------- problem constants ----------------
#define BATCH 32
#define NTOK  197
#define NPATCH 196
#define DMODEL 768
#define NLAYER 12
#define NHEAD 12
#define HDIM  64
#define ROWS  (BATCH*NTOK)     // 6304
#define CROWS (BATCH*NPATCH)   // 6272
#define DFF   3072
#define DQKV  2304
#define DOUT  512
#define NBH   (BATCH*NHEAD)

// per-layer weight slab offsets (bf16 elems)
#define WOFF_IN   ((size_t)0)
#define WOFF_OUT  ((size_t)(DQKV*DMODEL))
#define WOFF_FC   (WOFF_OUT + (size_t)(DMODEL*DMODEL))
#define WOFF_CP   (WOFF_FC + (size_t)(DFF*DMODEL))
#define WTOT      (WOFF_CP + (size_t)(DMODEL*DFF))      // 7,077,888 bf16

// workspace layout (float units)
#define WS_H    ((size_t)0)
#define WS_QKVB (WS_H + (size_t)ROWS*DMODEL)
#define WS_GB   (WS_QKVB + (size_t)ROWS*DQKV/2)
#define WS_TB   (WS_GB + (size_t)ROWS*DFF/2)
#define WS_WL   (WS_TB + (size_t)ROWS*DMODEL/2)          // 2 slabs of WTOT bf16 = WTOT floats
#define WS_PTS  (WS_WL + WTOT)
#define WS_ADD  (WS_PTS + (size_t)DOUT*DMODEL/2)

typedef unsigned short ushort_t;
typedef __attribute__((ext_vector_type(8))) short bf16x8;
typedef __attribute__((ext_vector_type(4))) float f32x4;

__device__ inline ushort_t bf16rn(float x) {
    uint32_t u = __builtin_bit_cast(uint32_t, x);
    uint32_t r = (u + 0x7FFFu + ((u >> 16) & 1u)) >> 16;
    return (ushort_t)r;
}

#define GLL(src, dst) __builtin_amdgcn_global_load_lds( \
    (const __attribute__((address_space(1))) void*)(src), \
    (__attribute__((address_space(3))) void*)(dst), 16, 0, 0)

// ---------------- small kernels ----------------

__global__ void im2col_bf16_k(const float* __restrict__ x, ushort_t* __restrict__ out) {
    int idx = blockIdx.x * 256 + threadIdx.x;
    if (idx >= CROWS * DMODEL / 4) return;
    int r  = idx / (DMODEL / 4);
    int k4 = (idx - r * (DMODEL / 4)) * 4;
    int b = r / NPATCH, p = r - b * NPATCH;
    int py = p / 14, px = p - py * 14;
    int c = k4 >> 8, rem = k4 & 255, i = rem >> 4, j = rem & 15;
    const float* xp = x + (((size_t)(b * 3 + c) * 224) + py * 16 + i) * 224 + px * 16 + j;
    float4 v = *(const float4*)xp;
    ushort4 hv = {bf16rn(v.x), bf16rn(v.y), bf16rn(v.z), bf16rn(v.w)};
    *(ushort4*)(out + (size_t)r * DMODEL + k4) = hv;
}

__global__ void cvt_w_k(const float* __restrict__ W, ushort_t* __restrict__ out, int NK) {
    int idx = (blockIdx.x * 256 + threadIdx.x) * 4;
    if (idx >= NK) return;
    float4 v = *(const float4*)(W + idx);
    ushort4 hv = {bf16rn(v.x), bf16rn(v.y), bf16rn(v.z), bf16rn(v.w)};
    *(ushort4*)(out + idx) = hv;
}

// one layer's 4 weight mats -> wl slab (used once, for layer 0)
__global__ void cvt_layer_k(const float* __restrict__ inW, const float* __restrict__ outW,
                            const float* __restrict__ fcW, const float* __restrict__ cpW,
                            ushort_t* __restrict__ wl) {
    size_t idx = ((size_t)blockIdx.x * 256 + threadIdx.x) * 4;
    if (idx >= WTOT) return;
    const float* src; size_t off;
    if (idx < WOFF_OUT)      { src = inW;  off = idx; }
    else if (idx < WOFF_FC)  { src = outW; off = idx - WOFF_OUT; }
    else if (idx < WOFF_CP)  { src = fcW;  off = idx - WOFF_FC; }
    else                     { src = cpW;  off = idx - WOFF_CP; }
    float4 v = *(const float4*)(src + off);
    ushort4 hv = {bf16rn(v.x), bf16rn(v.y), bf16rn(v.z), bf16rn(v.w)};
    *(ushort4*)(wl + idx) = hv;
}

__global__ void cvt_pT_k(const float* __restrict__ proj, ushort_t* __restrict__ out) {
    int idx = blockIdx.x * 256 + threadIdx.x;
    if (idx >= DOUT * DMODEL) return;
    int n = idx / DMODEL, k = idx - n * DMODEL;
    out[(size_t)n * DMODEL + k] = bf16rn(proj[(size_t)k * DOUT + n]);
}

__global__ void gauss_k(float* __restrict__ add) {
    int idx = blockIdx.x * 256 + threadIdx.x;
    if (idx >= NTOK * NTOK) return;
    int i = idx / NTOK, j = idx - i * NTOK;
    float v = 0.f;
    if (i > 0 && j > 0) {
        int p = i - 1, q = j - 1;
        int di = q / 14 - p / 14;
        int dj = q % 14 - p % 14;
        v = expf(-(float)(di * di + dj * dj) * 0.02f);
    }
    add[idx] = v;
}

// fused: embed (cls/conv + pos) then ln_pre, writes f32 h
__global__ __launch_bounds__(256) void embed_lnpre_k(const float* __restrict__ conv,
                                                     const float* __restrict__ cls,
                                                     const float* __restrict__ pos,
                                                     const float* __restrict__ w,
                                                     const float* __restrict__ b,
                                                     float* __restrict__ h) {
    int row = blockIdx.x, tid = threadIdx.x;
    int bb = row / NTOK, tok = row - bb * NTOK;
    float e[3];
    #pragma unroll
    for (int c = 0; c < 3; ++c) {
        int d = tid + c * 256;
        float v = (tok == 0) ? cls[d] : conv[((size_t)(bb * NPATCH + tok - 1)) * DMODEL + d];
        e[c] = v + pos[(size_t)tok * DMODEL + d];
    }
    float s = e[0] + e[1] + e[2];
    float s2 = e[0]*e[0] + e[1]*e[1] + e[2]*e[2];
    for (int o = 32; o > 0; o >>= 1) { s += __shfl_down(s, o); s2 += __shfl_down(s2, o); }
    __shared__ float red[8];
    int wid = tid >> 6;
    if ((tid & 63) == 0) { red[wid] = s; red[4 + wid] = s2; }
    __syncthreads();
    s  = red[0] + red[1] + red[2] + red[3];
    s2 = red[4] + red[5] + red[6] + red[7];
    float mean = s * (1.0f / 768.0f);
    float var  = s2 * (1.0f / 768.0f) - mean * mean;
    float rinv = rsqrtf(var + 1e-5f);
    float* o_ = h + (size_t)row * DMODEL;
    #pragma unroll
    for (int c = 0; c < 3; ++c) {
        int d = tid + c * 256;
        o_[d] = (e[c] - mean) * rinv * w[d] + b[d];
    }
}

__global__ __launch_bounds__(256) void ln768_bf16_k(const float* __restrict__ in, ushort_t* __restrict__ out,
                                                    const float* __restrict__ w, const float* __restrict__ b) {
    int row = blockIdx.x, tid = threadIdx.x;
    const float* x = in + (size_t)row * DMODEL;
    float v0 = x[tid], v1 = x[tid + 256], v2 = x[tid + 512];
    float s = v0 + v1 + v2;
    float s2 = v0 * v0 + v1 * v1 + v2 * v2;
    for (int o = 32; o > 0; o >>= 1) { s += __shfl_down(s, o); s2 += __shfl_down(s2, o); }
    __shared__ float red[8];
    int wid = tid >> 6;
    if ((tid & 63) == 0) { red[wid] = s; red[4 + wid] = s2; }
    __syncthreads();
    s  = red[0] + red[1] + red[2] + red[3];
    s2 = red[4] + red[5] + red[6] + red[7];
    float mean = s * (1.0f / 768.0f);
    float var  = s2 * (1.0f / 768.0f) - mean * mean;
    float rinv = rsqrtf(var + 1e-5f);
    ushort_t* o_ = out + (size_t)row * DMODEL;
    o_[tid]       = bf16rn((v0 - mean) * rinv * w[tid]       + b[tid]);
    o_[tid + 256] = bf16rn((v1 - mean) * rinv * w[tid + 256] + b[tid + 256]);
    o_[tid + 512] = bf16rn((v2 - mean) * rinv * w[tid + 512] + b[tid + 512]);
}

// ---------------- single-barrier DEPTH=3 MFMA GEMM + XCD swizzle + optional fused weight-cvt --------
// XCD swizzle decomposition: z OUTERMOST, m middle, n innermost.
//   - consecutive w on one XCD share the A-panel (mb) -> L2 locality (FETCH 57->47 MB, r13)
//   - same-(mb,nb) different-z pairs are nm*nn blocks apart -> no atomicAdd contention
//     (r13's z-innermost layout put them adjacent: WRITE +15 MB, dur +20%)
// Extra blocks (lin >= normal) stream-convert the NEXT layer's weights into cdst.
// mode 0: C = r + bias ; mode 1: OS = bf16(gelu(r+bias)) ; mode 3: atomicAdd(C, ...) ; mode 4: OS = bf16(r+bias)
template<int DEPTH>
__global__ __launch_bounds__(256) void gemm_mfma_k(
    const ushort_t* __restrict__ A, const ushort_t* __restrict__ W,
    const float* __restrict__ bias, float* __restrict__ C, ushort_t* __restrict__ OS,
    int M, int N, int K, int mode,
    const float* __restrict__ c0, const float* __restrict__ c1,
    const float* __restrict__ c2, const float* __restrict__ c3, ushort_t* __restrict__ cdst)
{
    __shared__ ushort_t As[DEPTH][128][32];
    __shared__ ushort_t Bs[DEPTH][128][32];
    int tid = threadIdx.x;

    int nm = (M + 127) >> 7;
    int nn = N >> 7;
    int nz = gridDim.z;
    int normal = nm * nn * nz;
    int lin = blockIdx.x + gridDim.x * (blockIdx.y + gridDim.y * blockIdx.z);
    int nwg = gridDim.x * gridDim.y * gridDim.z;

    if (lin >= normal) {
        // fused next-layer weight conversion (whole block diverges; no barriers used)
        int cvtb = nwg - normal;
        size_t i = (size_t)(lin - normal) * 256 + tid;
        size_t stride = (size_t)cvtb * 256;
        for (; i < WTOT / 4; i += stride) {
            size_t idx = i * 4;
            const float* src; size_t off;
            if (idx < WOFF_OUT)      { src = c0; off = idx; }
            else if (idx < WOFF_FC)  { src = c1; off = idx - WOFF_OUT; }
            else if (idx < WOFF_CP)  { src = c2; off = idx - WOFF_FC; }
            else                     { src = c3; off = idx - WOFF_CP; }
            float4 v = *(const float4*)(src + off);
            ushort4 hv = {bf16rn(v.x), bf16rn(v.y), bf16rn(v.z), bf16rn(v.w)};
            *(ushort4*)(cdst + idx) = hv;
        }
        return;
    }

    // bijective XCD swizzle (xcd = lin%8 hardware round-robin assumption)
    int q = normal >> 3, rr = normal & 7;
    int xcd = lin & 7, kk = lin >> 3;
    int w = (xcd < rr) ? (xcd * (q + 1) + kk) : (rr * (q + 1) + (xcd - rr) * q + kk);
    // z-outermost, m-middle, n-innermost
    int nmn = nm * nn;
    int zb = w / nmn;
    int rest = w - zb * nmn;
    int mb = rest / nn;
    int nb = rest - mb * nn;
    int m0 = mb * 128, n0 = nb * 128;

    int lane = tid & 63;
    int wave = tid >> 6;
    int wm = wave >> 1, wn = wave & 1;

    int klen = K / nz;
    int kbeg = zb * klen;
    int nt = klen / 32;

    f32x4 acc[4][4];
    #pragma unroll
    for (int i = 0; i < 4; ++i)
        #pragma unroll
        for (int j = 0; j < 4; ++j)
            acc[i][j] = (f32x4){0.f, 0.f, 0.f, 0.f};

    int srow = tid >> 2;
    int skq  = (((tid & 3) ^ ((tid >> 3) & 3)) * 8);      // pre-swizzled source slot
    int ar0 = m0 + srow;      if (ar0 > M - 1) ar0 = M - 1;
    int ar1 = m0 + srow + 64; if (ar1 > M - 1) ar1 = M - 1;
    const ushort_t* Ap0 = A + (size_t)ar0 * K + kbeg + skq;
    const ushort_t* Ap1 = A + (size_t)ar1 * K + kbeg + skq;
    const ushort_t* Wp0 = W + (size_t)(n0 + srow) * K + kbeg + skq;
    const ushort_t* Wp1 = W + (size_t)(n0 + srow + 64) * K + kbeg + skq;
    char* ldsA = (char*)As + tid * 16;
    char* ldsB = (char*)Bs + tid * 16;

    int fr = lane & 15, fq = lane >> 4;
    int rsl = (fq ^ ((fr >> 1) & 3)) * 8;                 // swizzled read slot

    #define STAGE(buf_, ko_) do {                         \
        GLL(Ap0 + (ko_), ldsA + (buf_) * 8192);           \
        GLL(Ap1 + (ko_), ldsA + (buf_) * 8192 + 4096);    \
        GLL(Wp0 + (ko_), ldsB + (buf_) * 8192);           \
        GLL(Wp1 + (ko_), ldsB + (buf_) * 8192 + 4096);    \
    } while (0)

    STAGE(0, 0);
    if (nt > 1) STAGE(1, 32);

    int cur = 0, pre = (DEPTH - 1) % DEPTH;
    for (int t = 0; t < nt; ++t) {
        if (t + 1 < nt) asm volatile("s_waitcnt vmcnt(4)" ::: "memory");
        else            asm volatile("s_waitcnt vmcnt(0)" ::: "memory");
        __builtin_amdgcn_s_barrier();
        if (t + DEPTH - 1 < nt) STAGE(pre, (size_t)(t + DEPTH - 1) * 32);
        bf16x8 a[4], b[4];
        #pragma unroll
        for (int fm = 0; fm < 4; ++fm)
            a[fm] = *(const bf16x8*)&As[cur][wm * 64 + fm * 16 + fr][rsl];
        #pragma unroll
        for (int fn = 0; fn < 4; ++fn)
            b[fn] = *(const bf16x8*)&Bs[cur][wn * 64 + fn * 16 + fr][rsl];
        #pragma unroll
        for (int fm = 0; fm < 4; ++fm)
            #pragma unroll
            for (int fn = 0; fn < 4; ++fn)
                acc[fm][fn] = __builtin_amdgcn_mfma_f32_16x16x32_bf16(a[fm], b[fn], acc[fm][fn], 0, 0, 0);
        cur = (cur + 1 == DEPTH) ? 0 : cur + 1;
        pre = (pre + 1 == DEPTH) ? 0 : pre + 1;
    }
    #undef STAGE

    // epilogue: D col = lane&15 (fr), row = fq*4 + j
    #pragma unroll
    for (int fn = 0; fn < 4; ++fn) {
        int ccol = n0 + wn * 64 + fn * 16 + fr;
        float bv = bias ? bias[ccol] : 0.f;
        if (mode == 3 && zb != 0) bv = 0.f;
        #pragma unroll
        for (int fm = 0; fm < 4; ++fm) {
            int crow0 = m0 + wm * 64 + fm * 16 + fq * 4;
            #pragma unroll
            for (int j = 0; j < 4; ++j) {
                int row = crow0 + j;
                if (row < M) {
                    float v = acc[fm][fn][j] + bv;
                    if (mode == 0) {
                        C[(size_t)row * N + ccol] = v;
                    } else if (mode == 3) {
                        atomicAdd(&C[(size_t)row * N + ccol], v);
                    } else if (mode == 4) {
                        OS[(size_t)row * N + ccol] = bf16rn(v);
                    } else {
                        v = v / (1.0f + expf(-1.702f * v));
                        OS[(size_t)row * N + ccol] = bf16rn(v);
                    }
                }
            }
        }
    }
}

// ---------------- fused MFMA flash attention, swapped-QK^T, 8 waves, q-split ----------------
__global__ __launch_bounds__(512, 4) void attn_fused_k(
    const ushort_t* __restrict__ qkvb, ushort_t* __restrict__ out,
    const float* __restrict__ addition, int qoff)
{
    __shared__ ushort_t Ks[208][72];
    __shared__ ushort_t Vt[64][232];
    __shared__ ushort_t Pb[8][2][16][40];
    int tid = threadIdx.x;
    int bh = blockIdx.x;
    int b = bh / NHEAD, hh = bh - b * NHEAD;
    const ushort_t* base = qkvb + (size_t)b * NTOK * DQKV + hh * HDIM;

    int lane = tid & 63, wave = tid >> 6;
    int fr = lane & 15, fq = lane >> 4;
    int qt = blockIdx.y * 8 + wave;

    bf16x8 qf0, qf1;
    if (qt < 13) {
        int qrow = qt * 16 + fr; if (qrow > NTOK - 1) qrow = NTOK - 1;
        const ushort_t* qp = base + (size_t)qrow * DQKV + qoff + fq * 8;
        qf0 = *(const bf16x8*)qp;
        qf1 = *(const bf16x8*)(qp + 32);
    }

    {
        int tt = tid >> 4, dq = tid & 15;
        #pragma unroll
        for (int pass = 0; pass < 7; ++pass) {
            int t = pass * 32 + tt;
            if (t < 208) {
                ushort4 kv = {0, 0, 0, 0}, vv = {0, 0, 0, 0};
                if (t < NTOK) {
                    kv = *(const ushort4*)(base + (size_t)t * DQKV + DMODEL + dq * 4);
                    vv = *(const ushort4*)(base + (size_t)t * DQKV + 2 * DMODEL + dq * 4);
                }
                *(ushort4*)&Ks[t][dq * 4] = kv;
                Vt[dq * 4 + 0][t] = vv.x;
                Vt[dq * 4 + 1][t] = vv.y;
                Vt[dq * 4 + 2][t] = vv.z;
                Vt[dq * 4 + 3][t] = vv.w;
            }
        }
        for (int z = tid; z < 64 * 24; z += 512) Vt[z / 24][208 + z % 24] = 0;
    }
    __syncthreads();

    if (qt < 13) {
        int i0 = qt * 16;
        int irow = i0 + fr; if (irow > NTOK - 1) irow = NTOK - 1;

        f32x4 s[13];
        #pragma unroll
        for (int jt = 0; jt < 13; ++jt) {
            bf16x8 k0 = *(const bf16x8*)&Ks[jt * 16 + fr][fq * 8];
            bf16x8 k1 = *(const bf16x8*)&Ks[jt * 16 + fr][32 + fq * 8];
            f32x4 a = {0.f, 0.f, 0.f, 0.f};
            a = __builtin_amdgcn_mfma_f32_16x16x32_bf16(k0, qf0, a, 0, 0, 0);
            a = __builtin_amdgcn_mfma_f32_16x16x32_bf16(k1, qf1, a, 0, 0, 0);
            s[jt] = a;
        }

        float mx = -1e30f;
        #pragma unroll
        for (int jt = 0; jt < 13; ++jt) {
            int jb = jt * 16 + fq * 4;
            #pragma unroll
            for (int jj = 0; jj < 4; ++jj) {
                int j = jb + jj;
                float v = s[jt][jj] * 0.125f;
                if (addition) v += addition[irow * NTOK + (j < NTOK ? j : NTOK - 1)];
                if (j >= NTOK) v = -1e30f;
                s[jt][jj] = v;
                mx = fmaxf(mx, v);
            }
        }
        mx = fmaxf(mx, __shfl_xor(mx, 16));
        mx = fmaxf(mx, __shfl_xor(mx, 32));
        float sum = 0.f;
        #pragma unroll
        for (int jt = 0; jt < 13; ++jt)
            #pragma unroll
            for (int jj = 0; jj < 4; ++jj) {
                float e = __expf(s[jt][jj] - mx);
                s[jt][jj] = e;
                sum += e;
            }
        sum += __shfl_xor(sum, 16);
        sum += __shfl_xor(sum, 32);
        float inv = 1.0f / sum;

        f32x4 o4[4];
        #pragma unroll
        for (int dt = 0; dt < 4; ++dt) o4[dt] = (f32x4){0.f, 0.f, 0.f, 0.f};

        #define WRITE_P(st_, buf_) do {                                              \
            int jA = 2 * (st_), jB = jA + 1;                                         \
            ushort4 wa = {bf16rn(s[jA][0] * inv), bf16rn(s[jA][1] * inv),            \
                          bf16rn(s[jA][2] * inv), bf16rn(s[jA][3] * inv)};           \
            ushort4 wb = {0, 0, 0, 0};                                               \
            if (jB < 13) wb = (ushort4){bf16rn(s[jB][0] * inv), bf16rn(s[jB][1] * inv), \
                                        bf16rn(s[jB][2] * inv), bf16rn(s[jB][3] * inv)}; \
            *(ushort4*)&Pb[wave][buf_][fr][fq * 4] = wa;                             \
            *(ushort4*)&Pb[wave][buf_][fr][16 + fq * 4] = wb;                        \
        } while (0)

        WRITE_P(0, 0);
        for (int st = 0; st < 7; ++st) {
            asm volatile("s_waitcnt lgkmcnt(0)" ::: "memory");
            bf16x8 pa = *(const bf16x8*)&Pb[wave][st & 1][fr][fq * 8];
            bf16x8 vf0 = *(const bf16x8*)&Vt[0 * 16 + fr][st * 32 + fq * 8];
            bf16x8 vf1 = *(const bf16x8*)&Vt[1 * 16 + fr][st * 32 + fq * 8];
            bf16x8 vf2 = *(const bf16x8*)&Vt[2 * 16 + fr][st * 32 + fq * 8];
            bf16x8 vf3 = *(const bf16x8*)&Vt[3 * 16 + fr][st * 32 + fq * 8];
            if (st < 6) WRITE_P(st + 1, (st + 1) & 1);
            o4[0] = __builtin_amdgcn_mfma_f32_16x16x32_bf16(pa, vf0, o4[0], 0, 0, 0);
            o4[1] = __builtin_amdgcn_mfma_f32_16x16x32_bf16(pa, vf1, o4[1], 0, 0, 0);
            o4[2] = __builtin_amdgcn_mfma_f32_16x16x32_bf16(pa, vf2, o4[2], 0, 0, 0);
            o4[3] = __builtin_amdgcn_mfma_f32_16x16x32_bf16(pa, vf3, o4[3], 0, 0, 0);
        }
        #undef WRITE_P

        #pragma unroll
        for (int jj = 0; jj < 4; ++jj) {
            int ir = i0 + fq * 4 + jj;
            if (ir < NTOK) {
                ushort_t* op = out + ((size_t)(b * NTOK + ir)) * DMODEL + hh * HDIM + fr;
                #pragma unroll
                for (int dt = 0; dt < 4; ++dt)
                    op[dt * 16] = bf16rn(o4[dt][jj]);
            }
        }
    }
}

#define NOCVT nullptr, nullptr, nullptr, nullptr, nullptr

// ---------------- launch ----------------
extern "C" void kernel_launch(void* const* d_in, const int* in_sizes, int n_in,
                              void* d_out, int out_size, void* d_ws, size_t ws_size,
                              hipStream_t stream) {
    const float* x        = (const float*)d_in[0];
    const float* conv1_w  = (const float*)d_in[1];
    const float* cls      = (const float*)d_in[2];
    const float* pos      = (const float*)d_in[3];
    const float* ln_pre_w = (const float*)d_in[4];
    const float* ln_pre_b = (const float*)d_in[5];
    const float* in_proj_w  = (const float*)d_in[6];
    const float* in_proj_b  = (const float*)d_in[7];
    const float* out_proj_w = (const float*)d_in[8];
    const float* out_proj_b = (const float*)d_in[9];
    const float* ln1_w = (const float*)d_in[10];
    const float* ln1_b = (const float*)d_in[11];
    const float* ln2_w = (const float*)d_in[12];
    const float* ln2_b = (const float*)d_in[13];
    const float* fc_w  = (const float*)d_in[14];
    const float* fc_b  = (const float*)d_in[15];
    const float* cproj_w = (const float*)d_in[16];
    const float* cproj_b = (const float*)d_in[17];
    const float* ln_post_w = (const float*)d_in[18];
    const float* ln_post_b = (const float*)d_in[19];
    const float* proj = (const float*)d_in[20];
    float* out = (float*)d_out;

    float* ws   = (float*)d_ws;
    float* h    = ws + WS_H;
    float* ctmp = ws + WS_QKVB;                          // conv f32 tmp (aliases qkvb)
    ushort_t* qkvb = (ushort_t*)(ws + WS_QKVB);
    ushort_t* gb   = (ushort_t*)(ws + WS_GB);
    ushort_t* tb   = (ushort_t*)(ws + WS_TB);
    ushort_t* wl   = (ushort_t*)(ws + WS_WL);            // 2 slabs of WTOT bf16
    ushort_t* pTs  = (ushort_t*)(ws + WS_PTS);
    float* add  = ws + WS_ADD;

    // conv weights staged in gb region (free until layer-0 fc)
    ushort_t* convw = gb;

    im2col_bf16_k<<<(CROWS * DMODEL / 4 + 255) / 256, 256, 0, stream>>>(x, tb);
    cvt_w_k<<<(DMODEL * DMODEL / 4 + 255) / 256, 256, 0, stream>>>(conv1_w, convw, DMODEL * DMODEL);
    hipMemsetAsync(ctmp, 0, (size_t)CROWS * DMODEL * sizeof(float), stream);
    gemm_mfma_k<3><<<dim3(49, 6, 2), 256, 0, stream>>>(
        tb, convw, nullptr, ctmp, nullptr, CROWS, DMODEL, DMODEL, 3, NOCVT);
    embed_lnpre_k<<<ROWS, 256, 0, stream>>>(ctmp, cls, pos, ln_pre_w, ln_pre_b, h);
    gauss_k<<<(NTOK * NTOK + 255) / 256, 256, 0, stream>>>(add);
    cvt_pT_k<<<(DOUT * DMODEL + 255) / 256, 256, 0, stream>>>(proj, pTs);
    // layer-0 weights up front
    cvt_layer_k<<<(int)(WTOT / 4 / 256), 256, 0, stream>>>(in_proj_w, out_proj_w, fc_w, cproj_w, wl);

    const int GY = (ROWS + 127) / 128;  // 50
    for (int l = 0; l < NLAYER; ++l) {
        ushort_t* wlp = wl + (size_t)(l & 1) * WTOT;
        ln768_bf16_k<<<ROWS, 256, 0, stream>>>(h, tb, ln1_w + l * DMODEL, ln1_b + l * DMODEL);
        if (l + 1 < NLAYER) {
            // qkv GEMM + 100 trailing blocks converting layer (l+1) weights into the other slab
            int l2 = l + 1;
            gemm_mfma_k<3><<<dim3(GY, DQKV / 128 + 2), 256, 0, stream>>>(
                tb, wlp + WOFF_IN, in_proj_b + (size_t)l * DQKV, nullptr, qkvb, ROWS, DQKV, DMODEL, 4,
                in_proj_w + (size_t)l2 * DQKV * DMODEL, out_proj_w + (size_t)l2 * DMODEL * DMODEL,
                fc_w + (size_t)l2 * DFF * DMODEL, cproj_w + (size_t)l2 * DMODEL * DFF,
                wl + (size_t)(l2 & 1) * WTOT);
        } else {
            gemm_mfma_k<3><<<dim3(GY, DQKV / 128), 256, 0, stream>>>(
                tb, wlp + WOFF_IN, in_proj_b + (size_t)l * DQKV, nullptr, qkvb, ROWS, DQKV, DMODEL, 4, NOCVT);
        }
        bool nac = (l == NLAYER - 1);
        attn_fused_k<<<dim3(NBH, 2), 512, 0, stream>>>(qkvb, tb, nac ? add : nullptr, nac ? DMODEL : 0);
        gemm_mfma_k<3><<<dim3(GY, DMODEL / 128, 2), 256, 0, stream>>>(
            tb, wlp + WOFF_OUT, out_proj_b + (size_t)l * DMODEL, h, nullptr, ROWS, DMODEL, DMODEL, 3, NOCVT);
        ln768_bf16_k<<<ROWS, 256, 0, stream>>>(h, tb, ln2_w + l * DMODEL, ln2_b + l * DMODEL);
        gemm_mfma_k<3><<<dim3(GY, DFF / 128), 256, 0, stream>>>(
            tb, wlp + WOFF_FC, fc_b + (size_t)l * DFF, nullptr, gb, ROWS, DFF, DMODEL, 1, NOCVT);
        gemm_mfma_k<3><<<dim3(GY, DMODEL / 128, 2), 256, 0, stream>>>(
            gb, wlp + WOFF_CP, cproj_b + (size_t)l * DMODEL, h, nullptr, ROWS, DMODEL, DFF, 3, NOCVT);
    }

    ln768_bf16_k<<<ROWS, 256, 0, stream>>>(h, tb, ln_post_w, ln_post_b);
    hipMemsetAsync(out, 0, (size_t)out_size * sizeof(float), stream);
    gemm_mfma_k<3><<<dim3(GY, DOUT / 128, 2), 256, 0, stream>>>(
        tb, pTs, nullptr, out, nullptr, ROWS, DOUT, DMODEL, 3, NOCVT);
}

// Round 15
// 3486.549 us; speedup vs baseline: 1.0327x; 1.0295x over previous
//
#include <hip/hip_runtime.h>
#include <hip/hip_bf16.h>
#include <math.h>

// ---------------- problem constants ----------------
#define BATCH 32
#define NTOK  197
#define NPATCH 196
#define DMODEL 768
#define NLAYER 12
#define NHEAD 12
#define HDIM  64
#define ROWS  (BATCH*NTOK)     // 6304
#define CROWS (BATCH*NPATCH)   // 6272
#define DFF   3072
#define DQKV  2304
#define DOUT  512
#define NBH   (BATCH*NHEAD)

// per-layer weight slab offsets (bf16 elems)
#define WOFF_IN   ((size_t)0)
#define WOFF_OUT  ((size_t)(DQKV*DMODEL))
#define WOFF_FC   (WOFF_OUT + (size_t)(DMODEL*DMODEL))
#define WOFF_CP   (WOFF_FC + (size_t)(DFF*DMODEL))
#define WTOT      (WOFF_CP + (size_t)(DMODEL*DFF))

// workspace layout (float units) — r9 layout
#define WS_H    ((size_t)0)
#define WS_QKVB (WS_H + (size_t)ROWS*DMODEL)
#define WS_GB   (WS_QKVB + (size_t)ROWS*DQKV/2)
#define WS_TB   (WS_GB + (size_t)ROWS*DFF/2)
#define WS_WL   (WS_TB + (size_t)ROWS*DMODEL/2)
#define WS_PTS  (WS_WL + WTOT/2)
#define WS_ADD  (WS_PTS + (size_t)DOUT*DMODEL/2)

typedef unsigned short ushort_t;
typedef __attribute__((ext_vector_type(8))) short bf16x8;
typedef __attribute__((ext_vector_type(4))) float f32x4;

__device__ inline ushort_t bf16rn(float x) {
    uint32_t u = __builtin_bit_cast(uint32_t, x);
    uint32_t r = (u + 0x7FFFu + ((u >> 16) & 1u)) >> 16;
    return (ushort_t)r;
}

#define GLL(src, dst) __builtin_amdgcn_global_load_lds( \
    (const __attribute__((address_space(1))) void*)(src), \
    (__attribute__((address_space(3))) void*)(dst), 16, 0, 0)

// ---------------- small kernels ----------------

__global__ void im2col_bf16_k(const float* __restrict__ x, ushort_t* __restrict__ out) {
    int idx = blockIdx.x * 256 + threadIdx.x;
    if (idx >= CROWS * DMODEL / 4) return;
    int r  = idx / (DMODEL / 4);
    int k4 = (idx - r * (DMODEL / 4)) * 4;
    int b = r / NPATCH, p = r - b * NPATCH;
    int py = p / 14, px = p - py * 14;
    int c = k4 >> 8, rem = k4 & 255, i = rem >> 4, j = rem & 15;
    const float* xp = x + (((size_t)(b * 3 + c) * 224) + py * 16 + i) * 224 + px * 16 + j;
    float4 v = *(const float4*)xp;
    ushort4 hv = {bf16rn(v.x), bf16rn(v.y), bf16rn(v.z), bf16rn(v.w)};
    *(ushort4*)(out + (size_t)r * DMODEL + k4) = hv;
}

__global__ void cvt_w_k(const float* __restrict__ W, ushort_t* __restrict__ out, int NK) {
    int idx = (blockIdx.x * 256 + threadIdx.x) * 4;
    if (idx >= NK) return;
    float4 v = *(const float4*)(W + idx);
    ushort4 hv = {bf16rn(v.x), bf16rn(v.y), bf16rn(v.z), bf16rn(v.w)};
    *(ushort4*)(out + idx) = hv;
}

// one layer's 4 weight mats -> wl slab (per-layer keeps the slab L2-warm for its 4 GEMMs)
__global__ void cvt_layer_k(const float* __restrict__ inW, const float* __restrict__ outW,
                            const float* __restrict__ fcW, const float* __restrict__ cpW,
                            ushort_t* __restrict__ wl) {
    size_t idx = ((size_t)blockIdx.x * 256 + threadIdx.x) * 4;
    if (idx >= WTOT) return;
    const float* src; size_t off;
    if (idx < WOFF_OUT)      { src = inW;  off = idx; }
    else if (idx < WOFF_FC)  { src = outW; off = idx - WOFF_OUT; }
    else if (idx < WOFF_CP)  { src = fcW;  off = idx - WOFF_FC; }
    else                     { src = cpW;  off = idx - WOFF_CP; }
    float4 v = *(const float4*)(src + off);
    ushort4 hv = {bf16rn(v.x), bf16rn(v.y), bf16rn(v.z), bf16rn(v.w)};
    *(ushort4*)(wl + idx) = hv;
}

__global__ void cvt_pT_k(const float* __restrict__ proj, ushort_t* __restrict__ out) {
    int idx = blockIdx.x * 256 + threadIdx.x;
    if (idx >= DOUT * DMODEL) return;
    int n = idx / DMODEL, k = idx - n * DMODEL;
    out[(size_t)n * DMODEL + k] = bf16rn(proj[(size_t)k * DOUT + n]);
}

__global__ void gauss_k(float* __restrict__ add) {
    int idx = blockIdx.x * 256 + threadIdx.x;
    if (idx >= NTOK * NTOK) return;
    int i = idx / NTOK, j = idx - i * NTOK;
    float v = 0.f;
    if (i > 0 && j > 0) {
        int p = i - 1, q = j - 1;
        int di = q / 14 - p / 14;
        int dj = q % 14 - p % 14;
        v = expf(-(float)(di * di + dj * dj) * 0.02f);
    }
    add[idx] = v;
}

// fused: embed (cls/conv + pos) then ln_pre, writes f32 h
__global__ __launch_bounds__(256) void embed_lnpre_k(const float* __restrict__ conv,
                                                     const float* __restrict__ cls,
                                                     const float* __restrict__ pos,
                                                     const float* __restrict__ w,
                                                     const float* __restrict__ b,
                                                     float* __restrict__ h) {
    int row = blockIdx.x, tid = threadIdx.x;
    int bb = row / NTOK, tok = row - bb * NTOK;
    float e[3];
    #pragma unroll
    for (int c = 0; c < 3; ++c) {
        int d = tid + c * 256;
        float v = (tok == 0) ? cls[d] : conv[((size_t)(bb * NPATCH + tok - 1)) * DMODEL + d];
        e[c] = v + pos[(size_t)tok * DMODEL + d];
    }
    float s = e[0] + e[1] + e[2];
    float s2 = e[0]*e[0] + e[1]*e[1] + e[2]*e[2];
    for (int o = 32; o > 0; o >>= 1) { s += __shfl_down(s, o); s2 += __shfl_down(s2, o); }
    __shared__ float red[8];
    int wid = tid >> 6;
    if ((tid & 63) == 0) { red[wid] = s; red[4 + wid] = s2; }
    __syncthreads();
    s  = red[0] + red[1] + red[2] + red[3];
    s2 = red[4] + red[5] + red[6] + red[7];
    float mean = s * (1.0f / 768.0f);
    float var  = s2 * (1.0f / 768.0f) - mean * mean;
    float rinv = rsqrtf(var + 1e-5f);
    float* o_ = h + (size_t)row * DMODEL;
    #pragma unroll
    for (int c = 0; c < 3; ++c) {
        int d = tid + c * 256;
        o_[d] = (e[c] - mean) * rinv * w[d] + b[d];
    }
}

__global__ __launch_bounds__(256) void ln768_bf16_k(const float* __restrict__ in, ushort_t* __restrict__ out,
                                                    const float* __restrict__ w, const float* __restrict__ b) {
    int row = blockIdx.x, tid = threadIdx.x;
    const float* x = in + (size_t)row * DMODEL;
    float v0 = x[tid], v1 = x[tid + 256], v2 = x[tid + 512];
    float s = v0 + v1 + v2;
    float s2 = v0 * v0 + v1 * v1 + v2 * v2;
    for (int o = 32; o > 0; o >>= 1) { s += __shfl_down(s, o); s2 += __shfl_down(s2, o); }
    __shared__ float red[8];
    int wid = tid >> 6;
    if ((tid & 63) == 0) { red[wid] = s; red[4 + wid] = s2; }
    __syncthreads();
    s  = red[0] + red[1] + red[2] + red[3];
    s2 = red[4] + red[5] + red[6] + red[7];
    float mean = s * (1.0f / 768.0f);
    float var  = s2 * (1.0f / 768.0f) - mean * mean;
    float rinv = rsqrtf(var + 1e-5f);
    ushort_t* o_ = out + (size_t)row * DMODEL;
    o_[tid]       = bf16rn((v0 - mean) * rinv * w[tid]       + b[tid]);
    o_[tid + 256] = bf16rn((v1 - mean) * rinv * w[tid + 256] + b[tid + 256]);
    o_[tid + 512] = bf16rn((v2 - mean) * rinv * w[tid + 512] + b[tid + 512]);
}

// ---------------- single-barrier DEPTH=3 MFMA GEMM (r9 structure, 3267us anchor) ----------------
// doswz=0: plain blockIdx decomposition (x=m, y=n, z=k-split) — REQUIRED for mode-3 atomic GEMMs
//          (r13/r14: swizzling these collapsed VALU 34->10%, Occ 24->15.6%, WRITE +25%).
// doswz=1: bijective XCD remap, z-outer/m-mid/n-inner — for streaming-store GEMMs (fc/qkv):
//          consecutive blocks on one XCD share the A-panel -> FETCH 94->~65 MB on fc.
// mode 0: C = r + bias ; mode 1: OS = bf16(gelu(r+bias)) ; mode 3: atomicAdd(C, ...) ; mode 4: OS = bf16(r+bias)
__global__ __launch_bounds__(256) void gemm_mfma_k(
    const ushort_t* __restrict__ A, const ushort_t* __restrict__ W,
    const float* __restrict__ bias, float* __restrict__ C, ushort_t* __restrict__ OS,
    int M, int N, int K, int mode, int doswz)
{
    __shared__ ushort_t As[3][128][32];
    __shared__ ushort_t Bs[3][128][32];
    int tid = threadIdx.x;
    int lane = tid & 63;
    int wave = tid >> 6;
    int wm = wave >> 1, wn = wave & 1;

    int mb, nb, zb;
    if (doswz) {
        int nm = gridDim.x, nn = gridDim.y, nz = gridDim.z;
        int normal = nm * nn * nz;
        int lin = blockIdx.x + gridDim.x * (blockIdx.y + gridDim.y * blockIdx.z);
        int q = normal >> 3, rr = normal & 7;
        int xcd = lin & 7, kk = lin >> 3;
        int w = (xcd < rr) ? (xcd * (q + 1) + kk) : (rr * (q + 1) + (xcd - rr) * q + kk);
        int nmn = nm * nn;
        zb = w / nmn;
        int rest = w - zb * nmn;
        mb = rest / nn;
        nb = rest - mb * nn;
    } else {
        mb = blockIdx.x; nb = blockIdx.y; zb = blockIdx.z;
    }
    int m0 = mb * 128, n0 = nb * 128;

    int klen = K / gridDim.z;
    int kbeg = zb * klen;
    int nt = klen / 32;

    f32x4 acc[4][4];
    #pragma unroll
    for (int i = 0; i < 4; ++i)
        #pragma unroll
        for (int j = 0; j < 4; ++j)
            acc[i][j] = (f32x4){0.f, 0.f, 0.f, 0.f};

    int srow = tid >> 2;
    int skq  = (((tid & 3) ^ ((tid >> 3) & 3)) * 8);      // pre-swizzled source slot
    int ar0 = m0 + srow;      if (ar0 > M - 1) ar0 = M - 1;
    int ar1 = m0 + srow + 64; if (ar1 > M - 1) ar1 = M - 1;
    const ushort_t* Ap0 = A + (size_t)ar0 * K + kbeg + skq;
    const ushort_t* Ap1 = A + (size_t)ar1 * K + kbeg + skq;
    const ushort_t* Wp0 = W + (size_t)(n0 + srow) * K + kbeg + skq;
    const ushort_t* Wp1 = W + (size_t)(n0 + srow + 64) * K + kbeg + skq;
    char* ldsA = (char*)As + tid * 16;
    char* ldsB = (char*)Bs + tid * 16;

    int fr = lane & 15, fq = lane >> 4;
    int rsl = (fq ^ ((fr >> 1) & 3)) * 8;                 // swizzled read slot

    #define STAGE(buf_, ko_) do {                         \
        GLL(Ap0 + (ko_), ldsA + (buf_) * 8192);           \
        GLL(Ap1 + (ko_), ldsA + (buf_) * 8192 + 4096);    \
        GLL(Wp0 + (ko_), ldsB + (buf_) * 8192);           \
        GLL(Wp1 + (ko_), ldsB + (buf_) * 8192 + 4096);    \
    } while (0)

    STAGE(0, 0);
    if (nt > 1) STAGE(1, 32);

    for (int t = 0; t < nt; ++t) {
        int cur = t % 3;
        if (t + 1 < nt) asm volatile("s_waitcnt vmcnt(4)" ::: "memory");
        else            asm volatile("s_waitcnt vmcnt(0)" ::: "memory");
        __builtin_amdgcn_s_barrier();
        if (t + 2 < nt) STAGE((t + 2) % 3, (size_t)(t + 2) * 32);
        bf16x8 a[4], b[4];
        #pragma unroll
        for (int fm = 0; fm < 4; ++fm)
            a[fm] = *(const bf16x8*)&As[cur][wm * 64 + fm * 16 + fr][rsl];
        #pragma unroll
        for (int fn = 0; fn < 4; ++fn)
            b[fn] = *(const bf16x8*)&Bs[cur][wn * 64 + fn * 16 + fr][rsl];
        #pragma unroll
        for (int fm = 0; fm < 4; ++fm)
            #pragma unroll
            for (int fn = 0; fn < 4; ++fn)
                acc[fm][fn] = __builtin_amdgcn_mfma_f32_16x16x32_bf16(a[fm], b[fn], acc[fm][fn], 0, 0, 0);
    }
    #undef STAGE

    // epilogue: D col = lane&15 (fr), row = fq*4 + j
    #pragma unroll
    for (int fn = 0; fn < 4; ++fn) {
        int ccol = n0 + wn * 64 + fn * 16 + fr;
        float bv = bias ? bias[ccol] : 0.f;
        if (mode == 3 && zb != 0) bv = 0.f;
        #pragma unroll
        for (int fm = 0; fm < 4; ++fm) {
            int crow0 = m0 + wm * 64 + fm * 16 + fq * 4;
            #pragma unroll
            for (int j = 0; j < 4; ++j) {
                int row = crow0 + j;
                if (row < M) {
                    float v = acc[fm][fn][j] + bv;
                    if (mode == 0) {
                        C[(size_t)row * N + ccol] = v;
                    } else if (mode == 3) {
                        atomicAdd(&C[(size_t)row * N + ccol], v);
                    } else if (mode == 4) {
                        OS[(size_t)row * N + ccol] = bf16rn(v);
                    } else {
                        v = v / (1.0f + expf(-1.702f * v));
                        OS[(size_t)row * N + ccol] = bf16rn(v);
                    }
                }
            }
        }
    }
}

// ---------------- fused MFMA flash attention, swapped-QK^T, 8 waves, q-split ----------------
__global__ __launch_bounds__(512, 4) void attn_fused_k(
    const ushort_t* __restrict__ qkvb, ushort_t* __restrict__ out,
    const float* __restrict__ addition, int qoff)
{
    __shared__ ushort_t Ks[208][72];
    __shared__ ushort_t Vt[64][232];
    __shared__ ushort_t Pb[8][2][16][40];
    int tid = threadIdx.x;
    int bh = blockIdx.x;
    int b = bh / NHEAD, hh = bh - b * NHEAD;
    const ushort_t* base = qkvb + (size_t)b * NTOK * DQKV + hh * HDIM;

    int lane = tid & 63, wave = tid >> 6;
    int fr = lane & 15, fq = lane >> 4;
    int qt = blockIdx.y * 8 + wave;

    bf16x8 qf0, qf1;
    if (qt < 13) {
        int qrow = qt * 16 + fr; if (qrow > NTOK - 1) qrow = NTOK - 1;
        const ushort_t* qp = base + (size_t)qrow * DQKV + qoff + fq * 8;
        qf0 = *(const bf16x8*)qp;
        qf1 = *(const bf16x8*)(qp + 32);
    }

    {
        int tt = tid >> 4, dq = tid & 15;
        #pragma unroll
        for (int pass = 0; pass < 7; ++pass) {
            int t = pass * 32 + tt;
            if (t < 208) {
                ushort4 kv = {0, 0, 0, 0}, vv = {0, 0, 0, 0};
                if (t < NTOK) {
                    kv = *(const ushort4*)(base + (size_t)t * DQKV + DMODEL + dq * 4);
                    vv = *(const ushort4*)(base + (size_t)t * DQKV + 2 * DMODEL + dq * 4);
                }
                *(ushort4*)&Ks[t][dq * 4] = kv;
                Vt[dq * 4 + 0][t] = vv.x;
                Vt[dq * 4 + 1][t] = vv.y;
                Vt[dq * 4 + 2][t] = vv.z;
                Vt[dq * 4 + 3][t] = vv.w;
            }
        }
        for (int z = tid; z < 64 * 24; z += 512) Vt[z / 24][208 + z % 24] = 0;
    }
    __syncthreads();

    if (qt < 13) {
        int i0 = qt * 16;
        int irow = i0 + fr; if (irow > NTOK - 1) irow = NTOK - 1;

        f32x4 s[13];
        #pragma unroll
        for (int jt = 0; jt < 13; ++jt) {
            bf16x8 k0 = *(const bf16x8*)&Ks[jt * 16 + fr][fq * 8];
            bf16x8 k1 = *(const bf16x8*)&Ks[jt * 16 + fr][32 + fq * 8];
            f32x4 a = {0.f, 0.f, 0.f, 0.f};
            a = __builtin_amdgcn_mfma_f32_16x16x32_bf16(k0, qf0, a, 0, 0, 0);
            a = __builtin_amdgcn_mfma_f32_16x16x32_bf16(k1, qf1, a, 0, 0, 0);
            s[jt] = a;
        }

        float mx = -1e30f;
        #pragma unroll
        for (int jt = 0; jt < 13; ++jt) {
            int jb = jt * 16 + fq * 4;
            #pragma unroll
            for (int jj = 0; jj < 4; ++jj) {
                int j = jb + jj;
                float v = s[jt][jj] * 0.125f;
                if (addition) v += addition[irow * NTOK + (j < NTOK ? j : NTOK - 1)];
                if (j >= NTOK) v = -1e30f;
                s[jt][jj] = v;
                mx = fmaxf(mx, v);
            }
        }
        mx = fmaxf(mx, __shfl_xor(mx, 16));
        mx = fmaxf(mx, __shfl_xor(mx, 32));
        float sum = 0.f;
        #pragma unroll
        for (int jt = 0; jt < 13; ++jt)
            #pragma unroll
            for (int jj = 0; jj < 4; ++jj) {
                float e = __expf(s[jt][jj] - mx);
                s[jt][jj] = e;
                sum += e;
            }
        sum += __shfl_xor(sum, 16);
        sum += __shfl_xor(sum, 32);
        float inv = 1.0f / sum;

        f32x4 o4[4];
        #pragma unroll
        for (int dt = 0; dt < 4; ++dt) o4[dt] = (f32x4){0.f, 0.f, 0.f, 0.f};

        #define WRITE_P(st_, buf_) do {                                              \
            int jA = 2 * (st_), jB = jA + 1;                                         \
            ushort4 wa = {bf16rn(s[jA][0] * inv), bf16rn(s[jA][1] * inv),            \
                          bf16rn(s[jA][2] * inv), bf16rn(s[jA][3] * inv)};           \
            ushort4 wb = {0, 0, 0, 0};                                               \
            if (jB < 13) wb = (ushort4){bf16rn(s[jB][0] * inv), bf16rn(s[jB][1] * inv), \
                                        bf16rn(s[jB][2] * inv), bf16rn(s[jB][3] * inv)}; \
            *(ushort4*)&Pb[wave][buf_][fr][fq * 4] = wa;                             \
            *(ushort4*)&Pb[wave][buf_][fr][16 + fq * 4] = wb;                        \
        } while (0)

        WRITE_P(0, 0);
        for (int st = 0; st < 7; ++st) {
            asm volatile("s_waitcnt lgkmcnt(0)" ::: "memory");
            bf16x8 pa = *(const bf16x8*)&Pb[wave][st & 1][fr][fq * 8];
            bf16x8 vf0 = *(const bf16x8*)&Vt[0 * 16 + fr][st * 32 + fq * 8];
            bf16x8 vf1 = *(const bf16x8*)&Vt[1 * 16 + fr][st * 32 + fq * 8];
            bf16x8 vf2 = *(const bf16x8*)&Vt[2 * 16 + fr][st * 32 + fq * 8];
            bf16x8 vf3 = *(const bf16x8*)&Vt[3 * 16 + fr][st * 32 + fq * 8];
            if (st < 6) WRITE_P(st + 1, (st + 1) & 1);
            o4[0] = __builtin_amdgcn_mfma_f32_16x16x32_bf16(pa, vf0, o4[0], 0, 0, 0);
            o4[1] = __builtin_amdgcn_mfma_f32_16x16x32_bf16(pa, vf1, o4[1], 0, 0, 0);
            o4[2] = __builtin_amdgcn_mfma_f32_16x16x32_bf16(pa, vf2, o4[2], 0, 0, 0);
            o4[3] = __builtin_amdgcn_mfma_f32_16x16x32_bf16(pa, vf3, o4[3], 0, 0, 0);
        }
        #undef WRITE_P

        #pragma unroll
        for (int jj = 0; jj < 4; ++jj) {
            int ir = i0 + fq * 4 + jj;
            if (ir < NTOK) {
                ushort_t* op = out + ((size_t)(b * NTOK + ir)) * DMODEL + hh * HDIM + fr;
                #pragma unroll
                for (int dt = 0; dt < 4; ++dt)
                    op[dt * 16] = bf16rn(o4[dt][jj]);
            }
        }
    }
}

// ---------------- launch ----------------
extern "C" void kernel_launch(void* const* d_in, const int* in_sizes, int n_in,
                              void* d_out, int out_size, void* d_ws, size_t ws_size,
                              hipStream_t stream) {
    const float* x        = (const float*)d_in[0];
    const float* conv1_w  = (const float*)d_in[1];
    const float* cls      = (const float*)d_in[2];
    const float* pos      = (const float*)d_in[3];
    const float* ln_pre_w = (const float*)d_in[4];
    const float* ln_pre_b = (const float*)d_in[5];
    const float* in_proj_w  = (const float*)d_in[6];
    const float* in_proj_b  = (const float*)d_in[7];
    const float* out_proj_w = (const float*)d_in[8];
    const float* out_proj_b = (const float*)d_in[9];
    const float* ln1_w = (const float*)d_in[10];
    const float* ln1_b = (const float*)d_in[11];
    const float* ln2_w = (const float*)d_in[12];
    const float* ln2_b = (const float*)d_in[13];
    const float* fc_w  = (const float*)d_in[14];
    const float* fc_b  = (const float*)d_in[15];
    const float* cproj_w = (const float*)d_in[16];
    const float* cproj_b = (const float*)d_in[17];
    const float* ln_post_w = (const float*)d_in[18];
    const float* ln_post_b = (const float*)d_in[19];
    const float* proj = (const float*)d_in[20];
    float* out = (float*)d_out;

    float* ws   = (float*)d_ws;
    float* h    = ws + WS_H;
    float* ctmp = ws + WS_QKVB;                          // conv f32 tmp (aliases qkvb)
    ushort_t* qkvb = (ushort_t*)(ws + WS_QKVB);
    ushort_t* gb   = (ushort_t*)(ws + WS_GB);
    ushort_t* tb   = (ushort_t*)(ws + WS_TB);
    ushort_t* wl   = (ushort_t*)(ws + WS_WL);
    ushort_t* pTs  = (ushort_t*)(ws + WS_PTS);
    float* add  = ws + WS_ADD;

    // conv weights staged in gb region (free until layer-0 fc)
    ushort_t* convw = gb;

    im2col_bf16_k<<<(CROWS * DMODEL / 4 + 255) / 256, 256, 0, stream>>>(x, tb);
    cvt_w_k<<<(DMODEL * DMODEL / 4 + 255) / 256, 256, 0, stream>>>(conv1_w, convw, DMODEL * DMODEL);
    gemm_mfma_k<<<dim3((CROWS + 127) / 128, DMODEL / 128), 256, 0, stream>>>(
        tb, convw, nullptr, ctmp, nullptr, CROWS, DMODEL, DMODEL, 0, 0);
    embed_lnpre_k<<<ROWS, 256, 0, stream>>>(ctmp, cls, pos, ln_pre_w, ln_pre_b, h);
    gauss_k<<<(NTOK * NTOK + 255) / 256, 256, 0, stream>>>(add);
    cvt_pT_k<<<(DOUT * DMODEL + 255) / 256, 256, 0, stream>>>(proj, pTs);

    const int GY = (ROWS + 127) / 128;  // 50
    for (int l = 0; l < NLAYER; ++l) {
        cvt_layer_k<<<(int)(WTOT / 4 / 256), 256, 0, stream>>>(
            in_proj_w + (size_t)l * DQKV * DMODEL, out_proj_w + (size_t)l * DMODEL * DMODEL,
            fc_w + (size_t)l * DFF * DMODEL, cproj_w + (size_t)l * DMODEL * DFF, wl);
        ln768_bf16_k<<<ROWS, 256, 0, stream>>>(h, tb, ln1_w + l * DMODEL, ln1_b + l * DMODEL);
        gemm_mfma_k<<<dim3(GY, DQKV / 128), 256, 0, stream>>>(
            tb, wl + WOFF_IN, in_proj_b + (size_t)l * DQKV, nullptr, qkvb, ROWS, DQKV, DMODEL, 4, 1);
        bool nac = (l == NLAYER - 1);
        attn_fused_k<<<dim3(NBH, 2), 512, 0, stream>>>(qkvb, tb, nac ? add : nullptr, nac ? DMODEL : 0);
        gemm_mfma_k<<<dim3(GY, DMODEL / 128, 2), 256, 0, stream>>>(
            tb, wl + WOFF_OUT, out_proj_b + (size_t)l * DMODEL, h, nullptr, ROWS, DMODEL, DMODEL, 3, 0);
        ln768_bf16_k<<<ROWS, 256, 0, stream>>>(h, tb, ln2_w + l * DMODEL, ln2_b + l * DMODEL);
        gemm_mfma_k<<<dim3(GY, DFF / 128), 256, 0, stream>>>(
            tb, wl + WOFF_FC, fc_b + (size_t)l * DFF, nullptr, gb, ROWS, DFF, DMODEL, 1, 1);
        gemm_mfma_k<<<dim3(GY, DMODEL / 128, 2), 256, 0, stream>>>(
            gb, wl + WOFF_CP, cproj_b + (size_t)l * DMODEL, h, nullptr, ROWS, DMODEL, DFF, 3, 0);
    }

    ln768_bf16_k<<<ROWS, 256, 0, stream>>>(h, tb, ln_post_w, ln_post_b);
    gemm_mfma_k<<<dim3(GY, DOUT / 128), 256, 0, stream>>>(
        tb, pTs, nullptr, out, nullptr, ROWS, DOUT, DMODEL, 0, 0);
}

// Round 16
// 3434.312 us; speedup vs baseline: 1.0484x; 1.0152x over previous
//
#include <hip/hip_runtime.h>
#include <hip/hip_bf16.h>
#include <math.h>

// ---------------- problem constants ----------------
#define BATCH 32
#define NTOK  197
#define NPATCH 196
#define DMODEL 768
#define NLAYER 12
#define NHEAD 12
#define HDIM  64
#define ROWS  (BATCH*NTOK)     // 6304
#define CROWS (BATCH*NPATCH)   // 6272
#define DFF   3072
#define DQKV  2304
#define DOUT  512
#define NBH   (BATCH*NHEAD)

// per-layer weight slab offsets (bf16 elems)
#define WOFF_IN   ((size_t)0)
#define WOFF_OUT  ((size_t)(DQKV*DMODEL))
#define WOFF_FC   (WOFF_OUT + (size_t)(DMODEL*DMODEL))
#define WOFF_CP   (WOFF_FC + (size_t)(DFF*DMODEL))
#define WTOT      (WOFF_CP + (size_t)(DMODEL*DFF))

// workspace layout (float units)
#define WS_H    ((size_t)0)
#define WS_QKVB (WS_H + (size_t)ROWS*DMODEL)
#define WS_GB   (WS_QKVB + (size_t)ROWS*DQKV/2)
#define WS_TB   (WS_GB + (size_t)ROWS*DFF/2)
#define WS_WL   (WS_TB + (size_t)ROWS*DMODEL/2)
#define WS_PTS  (WS_WL + WTOT/2)
#define WS_ADD  (WS_PTS + (size_t)DOUT*DMODEL/2)

typedef unsigned short ushort_t;
typedef __attribute__((ext_vector_type(8))) short bf16x8;
typedef __attribute__((ext_vector_type(4))) float f32x4;

__device__ inline ushort_t bf16rn(float x) {
    uint32_t u = __builtin_bit_cast(uint32_t, x);
    uint32_t r = (u + 0x7FFFu + ((u >> 16) & 1u)) >> 16;
    return (ushort_t)r;
}

#define GLL(src, dst) __builtin_amdgcn_global_load_lds( \
    (const __attribute__((address_space(1))) void*)(src), \
    (__attribute__((address_space(3))) void*)(dst), 16, 0, 0)

// ---------------- small kernels ----------------

__global__ void im2col_bf16_k(const float* __restrict__ x, ushort_t* __restrict__ out) {
    int idx = blockIdx.x * 256 + threadIdx.x;
    if (idx >= CROWS * DMODEL / 4) return;
    int r  = idx / (DMODEL / 4);
    int k4 = (idx - r * (DMODEL / 4)) * 4;
    int b = r / NPATCH, p = r - b * NPATCH;
    int py = p / 14, px = p - py * 14;
    int c = k4 >> 8, rem = k4 & 255, i = rem >> 4, j = rem & 15;
    const float* xp = x + (((size_t)(b * 3 + c) * 224) + py * 16 + i) * 224 + px * 16 + j;
    float4 v = *(const float4*)xp;
    ushort4 hv = {bf16rn(v.x), bf16rn(v.y), bf16rn(v.z), bf16rn(v.w)};
    *(ushort4*)(out + (size_t)r * DMODEL + k4) = hv;
}

__global__ void cvt_w_k(const float* __restrict__ W, ushort_t* __restrict__ out, int NK) {
    int idx = (blockIdx.x * 256 + threadIdx.x) * 4;
    if (idx >= NK) return;
    float4 v = *(const float4*)(W + idx);
    ushort4 hv = {bf16rn(v.x), bf16rn(v.y), bf16rn(v.z), bf16rn(v.w)};
    *(ushort4*)(out + idx) = hv;
}

// one layer's 4 weight mats -> wl slab (per-layer keeps the slab L2-warm for its 4 GEMMs)
__global__ void cvt_layer_k(const float* __restrict__ inW, const float* __restrict__ outW,
                            const float* __restrict__ fcW, const float* __restrict__ cpW,
                            ushort_t* __restrict__ wl) {
    size_t idx = ((size_t)blockIdx.x * 256 + threadIdx.x) * 4;
    if (idx >= WTOT) return;
    const float* src; size_t off;
    if (idx < WOFF_OUT)      { src = inW;  off = idx; }
    else if (idx < WOFF_FC)  { src = outW; off = idx - WOFF_OUT; }
    else if (idx < WOFF_CP)  { src = fcW;  off = idx - WOFF_FC; }
    else                     { src = cpW;  off = idx - WOFF_CP; }
    float4 v = *(const float4*)(src + off);
    ushort4 hv = {bf16rn(v.x), bf16rn(v.y), bf16rn(v.z), bf16rn(v.w)};
    *(ushort4*)(wl + idx) = hv;
}

__global__ void cvt_pT_k(const float* __restrict__ proj, ushort_t* __restrict__ out) {
    int idx = blockIdx.x * 256 + threadIdx.x;
    if (idx >= DOUT * DMODEL) return;
    int n = idx / DMODEL, k = idx - n * DMODEL;
    out[(size_t)n * DMODEL + k] = bf16rn(proj[(size_t)k * DOUT + n]);
}

__global__ void gauss_k(float* __restrict__ add) {
    int idx = blockIdx.x * 256 + threadIdx.x;
    if (idx >= NTOK * NTOK) return;
    int i = idx / NTOK, j = idx - i * NTOK;
    float v = 0.f;
    if (i > 0 && j > 0) {
        int p = i - 1, q = j - 1;
        int di = q / 14 - p / 14;
        int dj = q % 14 - p % 14;
        v = expf(-(float)(di * di + dj * dj) * 0.02f);
    }
    add[idx] = v;
}

// fused: embed (cls/conv + pos) then ln_pre, writes f32 h
__global__ __launch_bounds__(256) void embed_lnpre_k(const float* __restrict__ conv,
                                                     const float* __restrict__ cls,
                                                     const float* __restrict__ pos,
                                                     const float* __restrict__ w,
                                                     const float* __restrict__ b,
                                                     float* __restrict__ h) {
    int row = blockIdx.x, tid = threadIdx.x;
    int bb = row / NTOK, tok = row - bb * NTOK;
    float e[3];
    #pragma unroll
    for (int c = 0; c < 3; ++c) {
        int d = tid + c * 256;
        float v = (tok == 0) ? cls[d] : conv[((size_t)(bb * NPATCH + tok - 1)) * DMODEL + d];
        e[c] = v + pos[(size_t)tok * DMODEL + d];
    }
    float s = e[0] + e[1] + e[2];
    float s2 = e[0]*e[0] + e[1]*e[1] + e[2]*e[2];
    for (int o = 32; o > 0; o >>= 1) { s += __shfl_down(s, o); s2 += __shfl_down(s2, o); }
    __shared__ float red[8];
    int wid = tid >> 6;
    if ((tid & 63) == 0) { red[wid] = s; red[4 + wid] = s2; }
    __syncthreads();
    s  = red[0] + red[1] + red[2] + red[3];
    s2 = red[4] + red[5] + red[6] + red[7];
    float mean = s * (1.0f / 768.0f);
    float var  = s2 * (1.0f / 768.0f) - mean * mean;
    float rinv = rsqrtf(var + 1e-5f);
    float* o_ = h + (size_t)row * DMODEL;
    #pragma unroll
    for (int c = 0; c < 3; ++c) {
        int d = tid + c * 256;
        o_[d] = (e[c] - mean) * rinv * w[d] + b[d];
    }
}

__global__ __launch_bounds__(256) void ln768_bf16_k(const float* __restrict__ in, ushort_t* __restrict__ out,
                                                    const float* __restrict__ w, const float* __restrict__ b) {
    int row = blockIdx.x, tid = threadIdx.x;
    const float* x = in + (size_t)row * DMODEL;
    float v0 = x[tid], v1 = x[tid + 256], v2 = x[tid + 512];
    float s = v0 + v1 + v2;
    float s2 = v0 * v0 + v1 * v1 + v2 * v2;
    for (int o = 32; o > 0; o >>= 1) { s += __shfl_down(s, o); s2 += __shfl_down(s2, o); }
    __shared__ float red[8];
    int wid = tid >> 6;
    if ((tid & 63) == 0) { red[wid] = s; red[4 + wid] = s2; }
    __syncthreads();
    s  = red[0] + red[1] + red[2] + red[3];
    s2 = red[4] + red[5] + red[6] + red[7];
    float mean = s * (1.0f / 768.0f);
    float var  = s2 * (1.0f / 768.0f) - mean * mean;
    float rinv = rsqrtf(var + 1e-5f);
    ushort_t* o_ = out + (size_t)row * DMODEL;
    o_[tid]       = bf16rn((v0 - mean) * rinv * w[tid]       + b[tid]);
    o_[tid + 256] = bf16rn((v1 - mean) * rinv * w[tid + 256] + b[tid + 256]);
    o_[tid + 512] = bf16rn((v2 - mean) * rinv * w[tid + 512] + b[tid + 512]);
}

// ---------------- old 128x128 GEMM (conv / final projection only) ----------------
__global__ __launch_bounds__(256) void gemm_mfma_k(
    const ushort_t* __restrict__ A, const ushort_t* __restrict__ W,
    const float* __restrict__ bias, float* __restrict__ C, ushort_t* __restrict__ OS,
    int M, int N, int K, int mode)
{
    __shared__ ushort_t As[3][128][32];
    __shared__ ushort_t Bs[3][128][32];
    int tid = threadIdx.x;
    int lane = tid & 63;
    int wave = tid >> 6;
    int wm = wave >> 1, wn = wave & 1;
    int m0 = blockIdx.x * 128, n0 = blockIdx.y * 128;

    int klen = K / gridDim.z;
    int kbeg = blockIdx.z * klen;
    int nt = klen / 32;

    f32x4 acc[4][4];
    #pragma unroll
    for (int i = 0; i < 4; ++i)
        #pragma unroll
        for (int j = 0; j < 4; ++j)
            acc[i][j] = (f32x4){0.f, 0.f, 0.f, 0.f};

    int srow = tid >> 2;
    int skq  = (((tid & 3) ^ ((tid >> 3) & 3)) * 8);
    int ar0 = m0 + srow;      if (ar0 > M - 1) ar0 = M - 1;
    int ar1 = m0 + srow + 64; if (ar1 > M - 1) ar1 = M - 1;
    const ushort_t* Ap0 = A + (size_t)ar0 * K + kbeg + skq;
    const ushort_t* Ap1 = A + (size_t)ar1 * K + kbeg + skq;
    const ushort_t* Wp0 = W + (size_t)(n0 + srow) * K + kbeg + skq;
    const ushort_t* Wp1 = W + (size_t)(n0 + srow + 64) * K + kbeg + skq;
    char* ldsA = (char*)As + tid * 16;
    char* ldsB = (char*)Bs + tid * 16;

    int fr = lane & 15, fq = lane >> 4;
    int rsl = (fq ^ ((fr >> 1) & 3)) * 8;

    #define STAGE(buf_, ko_) do {                         \
        GLL(Ap0 + (ko_), ldsA + (buf_) * 8192);           \
        GLL(Ap1 + (ko_), ldsA + (buf_) * 8192 + 4096);    \
        GLL(Wp0 + (ko_), ldsB + (buf_) * 8192);           \
        GLL(Wp1 + (ko_), ldsB + (buf_) * 8192 + 4096);    \
    } while (0)

    STAGE(0, 0);
    if (nt > 1) STAGE(1, 32);

    for (int t = 0; t < nt; ++t) {
        int cur = t % 3;
        if (t + 1 < nt) asm volatile("s_waitcnt vmcnt(4)" ::: "memory");
        else            asm volatile("s_waitcnt vmcnt(0)" ::: "memory");
        __builtin_amdgcn_s_barrier();
        if (t + 2 < nt) STAGE((t + 2) % 3, (size_t)(t + 2) * 32);
        bf16x8 a[4], b[4];
        #pragma unroll
        for (int fm = 0; fm < 4; ++fm)
            a[fm] = *(const bf16x8*)&As[cur][wm * 64 + fm * 16 + fr][rsl];
        #pragma unroll
        for (int fn = 0; fn < 4; ++fn)
            b[fn] = *(const bf16x8*)&Bs[cur][wn * 64 + fn * 16 + fr][rsl];
        #pragma unroll
        for (int fm = 0; fm < 4; ++fm)
            #pragma unroll
            for (int fn = 0; fn < 4; ++fn)
                acc[fm][fn] = __builtin_amdgcn_mfma_f32_16x16x32_bf16(a[fm], b[fn], acc[fm][fn], 0, 0, 0);
    }
    #undef STAGE

    #pragma unroll
    for (int fn = 0; fn < 4; ++fn) {
        int ccol = n0 + wn * 64 + fn * 16 + fr;
        float bv = bias ? bias[ccol] : 0.f;
        #pragma unroll
        for (int fm = 0; fm < 4; ++fm) {
            int crow0 = m0 + wm * 64 + fm * 16 + fq * 4;
            #pragma unroll
            for (int j = 0; j < 4; ++j) {
                int row = crow0 + j;
                if (row < M) {
                    float v = acc[fm][fn][j] + bv;
                    if (mode == 0) C[(size_t)row * N + ccol] = v;
                    else           OS[(size_t)row * N + ccol] = bf16rn(v);
                }
            }
        }
    }
}

// ---------------- NEW 256x128 GEMM, 8 waves, single-barrier DEPTH=3 ----------------
// Same proven loop; per-wave code identical (4m x 2n quadrants of 64x64). 3 GLL/thread per
// stage -> vmcnt(3). LDS 72 KB -> 2 blocks/CU = 16 waves/CU (vs ~9 at 128x128); A-traffic
// per output halves (FLOP/staged-byte 64 -> 85).
// mode 0: C=r+bias ; 1: OS=bf16(gelu) ; 3: atomicAdd ; 4: OS=bf16(r+bias)
__global__ __launch_bounds__(512) void gemm_mfma2_k(
    const ushort_t* __restrict__ A, const ushort_t* __restrict__ W,
    const float* __restrict__ bias, float* __restrict__ C, ushort_t* __restrict__ OS,
    int M, int N, int K, int mode, int doswz)
{
    __shared__ ushort_t As[3][256][32];   // 48 KB
    __shared__ ushort_t Bs[3][128][32];   // 24 KB
    int tid = threadIdx.x;
    int lane = tid & 63;
    int wave = tid >> 6;
    int wm = wave >> 1, wn = wave & 1;    // wm 0..3, wn 0..1

    int mb, nb, zb;
    if (doswz) {
        int nm = gridDim.x, nn = gridDim.y, nz = gridDim.z;
        int normal = nm * nn * nz;
        int lin = blockIdx.x + gridDim.x * (blockIdx.y + gridDim.y * blockIdx.z);
        int q = normal >> 3, rr = normal & 7;
        int xcd = lin & 7, kk = lin >> 3;
        int w = (xcd < rr) ? (xcd * (q + 1) + kk) : (rr * (q + 1) + (xcd - rr) * q + kk);
        int nmn = nm * nn;
        zb = w / nmn;
        int rest = w - zb * nmn;
        mb = rest / nn;
        nb = rest - mb * nn;
    } else {
        mb = blockIdx.x; nb = blockIdx.y; zb = blockIdx.z;
    }
    int m0 = mb * 256, n0 = nb * 128;

    int klen = K / gridDim.z;
    int kbeg = zb * klen;
    int nt = klen / 32;

    f32x4 acc[4][4];
    #pragma unroll
    for (int i = 0; i < 4; ++i)
        #pragma unroll
        for (int j = 0; j < 4; ++j)
            acc[i][j] = (f32x4){0.f, 0.f, 0.f, 0.f};

    int srow = tid >> 2;                                   // 0..127
    int skq  = (((tid & 3) ^ ((tid >> 3) & 3)) * 8);       // pre-swizzled source slot
    int ar0 = m0 + srow;        if (ar0 > M - 1) ar0 = M - 1;
    int ar1 = m0 + srow + 128;  if (ar1 > M - 1) ar1 = M - 1;
    const ushort_t* Ap0 = A + (size_t)ar0 * K + kbeg + skq;
    const ushort_t* Ap1 = A + (size_t)ar1 * K + kbeg + skq;
    const ushort_t* Wp0 = W + (size_t)(n0 + srow) * K + kbeg + skq;
    char* ldsA = (char*)As + tid * 16;    // buf stride 16384; rows 0..127 then +8192 rows 128..255
    char* ldsB = (char*)Bs + tid * 16;    // buf stride 8192

    int fr = lane & 15, fq = lane >> 4;
    int rsl = (fq ^ ((fr >> 1) & 3)) * 8;                  // swizzled read slot

    #define STAGE2(buf_, ko_) do {                          \
        GLL(Ap0 + (ko_), ldsA + (buf_) * 16384);            \
        GLL(Ap1 + (ko_), ldsA + (buf_) * 16384 + 8192);     \
        GLL(Wp0 + (ko_), ldsB + (buf_) * 8192);             \
    } while (0)

    STAGE2(0, 0);
    if (nt > 1) STAGE2(1, 32);

    for (int t = 0; t < nt; ++t) {
        int cur = t % 3;
        if (t + 1 < nt) asm volatile("s_waitcnt vmcnt(3)" ::: "memory");
        else            asm volatile("s_waitcnt vmcnt(0)" ::: "memory");
        __builtin_amdgcn_s_barrier();
        if (t + 2 < nt) STAGE2((t + 2) % 3, (size_t)(t + 2) * 32);
        bf16x8 a[4], b[4];
        #pragma unroll
        for (int fm = 0; fm < 4; ++fm)
            a[fm] = *(const bf16x8*)&As[cur][wm * 64 + fm * 16 + fr][rsl];
        #pragma unroll
        for (int fn = 0; fn < 4; ++fn)
            b[fn] = *(const bf16x8*)&Bs[cur][wn * 64 + fn * 16 + fr][rsl];
        #pragma unroll
        for (int fm = 0; fm < 4; ++fm)
            #pragma unroll
            for (int fn = 0; fn < 4; ++fn)
                acc[fm][fn] = __builtin_amdgcn_mfma_f32_16x16x32_bf16(a[fm], b[fn], acc[fm][fn], 0, 0, 0);
    }
    #undef STAGE2

    // epilogue: D col = lane&15 (fr), row = fq*4 + j
    #pragma unroll
    for (int fn = 0; fn < 4; ++fn) {
        int ccol = n0 + wn * 64 + fn * 16 + fr;
        float bv = bias ? bias[ccol] : 0.f;
        if (mode == 3 && zb != 0) bv = 0.f;
        #pragma unroll
        for (int fm = 0; fm < 4; ++fm) {
            int crow0 = m0 + wm * 64 + fm * 16 + fq * 4;
            #pragma unroll
            for (int j = 0; j < 4; ++j) {
                int row = crow0 + j;
                if (row < M) {
                    float v = acc[fm][fn][j] + bv;
                    if (mode == 0) {
                        C[(size_t)row * N + ccol] = v;
                    } else if (mode == 3) {
                        atomicAdd(&C[(size_t)row * N + ccol], v);
                    } else if (mode == 4) {
                        OS[(size_t)row * N + ccol] = bf16rn(v);
                    } else {
                        v = v / (1.0f + expf(-1.702f * v));
                        OS[(size_t)row * N + ccol] = bf16rn(v);
                    }
                }
            }
        }
    }
}

// ---------------- fused MFMA flash attention, swapped-QK^T, 8 waves, q-split ----------------
__global__ __launch_bounds__(512, 4) void attn_fused_k(
    const ushort_t* __restrict__ qkvb, ushort_t* __restrict__ out,
    const float* __restrict__ addition, int qoff)
{
    __shared__ ushort_t Ks[208][72];
    __shared__ ushort_t Vt[64][232];
    __shared__ ushort_t Pb[8][2][16][40];
    int tid = threadIdx.x;
    int bh = blockIdx.x;
    int b = bh / NHEAD, hh = bh - b * NHEAD;
    const ushort_t* base = qkvb + (size_t)b * NTOK * DQKV + hh * HDIM;

    int lane = tid & 63, wave = tid >> 6;
    int fr = lane & 15, fq = lane >> 4;
    int qt = blockIdx.y * 8 + wave;

    bf16x8 qf0, qf1;
    if (qt < 13) {
        int qrow = qt * 16 + fr; if (qrow > NTOK - 1) qrow = NTOK - 1;
        const ushort_t* qp = base + (size_t)qrow * DQKV + qoff + fq * 8;
        qf0 = *(const bf16x8*)qp;
        qf1 = *(const bf16x8*)(qp + 32);
    }

    {
        int tt = tid >> 4, dq = tid & 15;
        #pragma unroll
        for (int pass = 0; pass < 7; ++pass) {
            int t = pass * 32 + tt;
            if (t < 208) {
                ushort4 kv = {0, 0, 0, 0}, vv = {0, 0, 0, 0};
                if (t < NTOK) {
                    kv = *(const ushort4*)(base + (size_t)t * DQKV + DMODEL + dq * 4);
                    vv = *(const ushort4*)(base + (size_t)t * DQKV + 2 * DMODEL + dq * 4);
                }
                *(ushort4*)&Ks[t][dq * 4] = kv;
                Vt[dq * 4 + 0][t] = vv.x;
                Vt[dq * 4 + 1][t] = vv.y;
                Vt[dq * 4 + 2][t] = vv.z;
                Vt[dq * 4 + 3][t] = vv.w;
            }
        }
        for (int z = tid; z < 64 * 24; z += 512) Vt[z / 24][208 + z % 24] = 0;
    }
    __syncthreads();

    if (qt < 13) {
        int i0 = qt * 16;
        int irow = i0 + fr; if (irow > NTOK - 1) irow = NTOK - 1;

        f32x4 s[13];
        #pragma unroll
        for (int jt = 0; jt < 13; ++jt) {
            bf16x8 k0 = *(const bf16x8*)&Ks[jt * 16 + fr][fq * 8];
            bf16x8 k1 = *(const bf16x8*)&Ks[jt * 16 + fr][32 + fq * 8];
            f32x4 a = {0.f, 0.f, 0.f, 0.f};
            a = __builtin_amdgcn_mfma_f32_16x16x32_bf16(k0, qf0, a, 0, 0, 0);
            a = __builtin_amdgcn_mfma_f32_16x16x32_bf16(k1, qf1, a, 0, 0, 0);
            s[jt] = a;
        }

        float mx = -1e30f;
        #pragma unroll
        for (int jt = 0; jt < 13; ++jt) {
            int jb = jt * 16 + fq * 4;
            #pragma unroll
            for (int jj = 0; jj < 4; ++jj) {
                int j = jb + jj;
                float v = s[jt][jj] * 0.125f;
                if (addition) v += addition[irow * NTOK + (j < NTOK ? j : NTOK - 1)];
                if (j >= NTOK) v = -1e30f;
                s[jt][jj] = v;
                mx = fmaxf(mx, v);
            }
        }
        mx = fmaxf(mx, __shfl_xor(mx, 16));
        mx = fmaxf(mx, __shfl_xor(mx, 32));
        float sum = 0.f;
        #pragma unroll
        for (int jt = 0; jt < 13; ++jt)
            #pragma unroll
            for (int jj = 0; jj < 4; ++jj) {
                float e = __expf(s[jt][jj] - mx);
                s[jt][jj] = e;
                sum += e;
            }
        sum += __shfl_xor(sum, 16);
        sum += __shfl_xor(sum, 32);
        float inv = 1.0f / sum;

        f32x4 o4[4];
        #pragma unroll
        for (int dt = 0; dt < 4; ++dt) o4[dt] = (f32x4){0.f, 0.f, 0.f, 0.f};

        #define WRITE_P(st_, buf_) do {                                              \
            int jA = 2 * (st_), jB = jA + 1;                                         \
            ushort4 wa = {bf16rn(s[jA][0] * inv), bf16rn(s[jA][1] * inv),            \
                          bf16rn(s[jA][2] * inv), bf16rn(s[jA][3] * inv)};           \
            ushort4 wb = {0, 0, 0, 0};                                               \
            if (jB < 13) wb = (ushort4){bf16rn(s[jB][0] * inv), bf16rn(s[jB][1] * inv), \
                                        bf16rn(s[jB][2] * inv), bf16rn(s[jB][3] * inv)}; \
            *(ushort4*)&Pb[wave][buf_][fr][fq * 4] = wa;                             \
            *(ushort4*)&Pb[wave][buf_][fr][16 + fq * 4] = wb;                        \
        } while (0)

        WRITE_P(0, 0);
        for (int st = 0; st < 7; ++st) {
            asm volatile("s_waitcnt lgkmcnt(0)" ::: "memory");
            bf16x8 pa = *(const bf16x8*)&Pb[wave][st & 1][fr][fq * 8];
            bf16x8 vf0 = *(const bf16x8*)&Vt[0 * 16 + fr][st * 32 + fq * 8];
            bf16x8 vf1 = *(const bf16x8*)&Vt[1 * 16 + fr][st * 32 + fq * 8];
            bf16x8 vf2 = *(const bf16x8*)&Vt[2 * 16 + fr][st * 32 + fq * 8];
            bf16x8 vf3 = *(const bf16x8*)&Vt[3 * 16 + fr][st * 32 + fq * 8];
            if (st < 6) WRITE_P(st + 1, (st + 1) & 1);
            o4[0] = __builtin_amdgcn_mfma_f32_16x16x32_bf16(pa, vf0, o4[0], 0, 0, 0);
            o4[1] = __builtin_amdgcn_mfma_f32_16x16x32_bf16(pa, vf1, o4[1], 0, 0, 0);
            o4[2] = __builtin_amdgcn_mfma_f32_16x16x32_bf16(pa, vf2, o4[2], 0, 0, 0);
            o4[3] = __builtin_amdgcn_mfma_f32_16x16x32_bf16(pa, vf3, o4[3], 0, 0, 0);
        }
        #undef WRITE_P

        #pragma unroll
        for (int jj = 0; jj < 4; ++jj) {
            int ir = i0 + fq * 4 + jj;
            if (ir < NTOK) {
                ushort_t* op = out + ((size_t)(b * NTOK + ir)) * DMODEL + hh * HDIM + fr;
                #pragma unroll
                for (int dt = 0; dt < 4; ++dt)
                    op[dt * 16] = bf16rn(o4[dt][jj]);
            }
        }
    }
}

// ---------------- launch ----------------
extern "C" void kernel_launch(void* const* d_in, const int* in_sizes, int n_in,
                              void* d_out, int out_size, void* d_ws, size_t ws_size,
                              hipStream_t stream) {
    const float* x        = (const float*)d_in[0];
    const float* conv1_w  = (const float*)d_in[1];
    const float* cls      = (const float*)d_in[2];
    const float* pos      = (const float*)d_in[3];
    const float* ln_pre_w = (const float*)d_in[4];
    const float* ln_pre_b = (const float*)d_in[5];
    const float* in_proj_w  = (const float*)d_in[6];
    const float* in_proj_b  = (const float*)d_in[7];
    const float* out_proj_w = (const float*)d_in[8];
    const float* out_proj_b = (const float*)d_in[9];
    const float* ln1_w = (const float*)d_in[10];
    const float* ln1_b = (const float*)d_in[11];
    const float* ln2_w = (const float*)d_in[12];
    const float* ln2_b = (const float*)d_in[13];
    const float* fc_w  = (const float*)d_in[14];
    const float* fc_b  = (const float*)d_in[15];
    const float* cproj_w = (const float*)d_in[16];
    const float* cproj_b = (const float*)d_in[17];
    const float* ln_post_w = (const float*)d_in[18];
    const float* ln_post_b = (const float*)d_in[19];
    const float* proj = (const float*)d_in[20];
    float* out = (float*)d_out;

    float* ws   = (float*)d_ws;
    float* h    = ws + WS_H;
    float* ctmp = ws + WS_QKVB;                          // conv f32 tmp (aliases qkvb)
    ushort_t* qkvb = (ushort_t*)(ws + WS_QKVB);
    ushort_t* gb   = (ushort_t*)(ws + WS_GB);
    ushort_t* tb   = (ushort_t*)(ws + WS_TB);
    ushort_t* wl   = (ushort_t*)(ws + WS_WL);
    ushort_t* pTs  = (ushort_t*)(ws + WS_PTS);
    float* add  = ws + WS_ADD;

    // conv weights staged in gb region (free until layer-0 fc)
    ushort_t* convw = gb;

    im2col_bf16_k<<<(CROWS * DMODEL / 4 + 255) / 256, 256, 0, stream>>>(x, tb);
    cvt_w_k<<<(DMODEL * DMODEL / 4 + 255) / 256, 256, 0, stream>>>(conv1_w, convw, DMODEL * DMODEL);
    gemm_mfma_k<<<dim3((CROWS + 127) / 128, DMODEL / 128), 256, 0, stream>>>(
        tb, convw, nullptr, ctmp, nullptr, CROWS, DMODEL, DMODEL, 0);
    embed_lnpre_k<<<ROWS, 256, 0, stream>>>(ctmp, cls, pos, ln_pre_w, ln_pre_b, h);
    gauss_k<<<(NTOK * NTOK + 255) / 256, 256, 0, stream>>>(add);
    cvt_pT_k<<<(DOUT * DMODEL + 255) / 256, 256, 0, stream>>>(proj, pTs);

    const int GM = (ROWS + 255) / 256;  // 25
    const int GY = (ROWS + 127) / 128;  // 50
    for (int l = 0; l < NLAYER; ++l) {
        cvt_layer_k<<<(int)(WTOT / 4 / 256), 256, 0, stream>>>(
            in_proj_w + (size_t)l * DQKV * DMODEL, out_proj_w + (size_t)l * DMODEL * DMODEL,
            fc_w + (size_t)l * DFF * DMODEL, cproj_w + (size_t)l * DMODEL * DFF, wl);
        ln768_bf16_k<<<ROWS, 256, 0, stream>>>(h, tb, ln1_w + l * DMODEL, ln1_b + l * DMODEL);
        gemm_mfma2_k<<<dim3(GM, DQKV / 128), 512, 0, stream>>>(
            tb, wl + WOFF_IN, in_proj_b + (size_t)l * DQKV, nullptr, qkvb, ROWS, DQKV, DMODEL, 4, 1);
        bool nac = (l == NLAYER - 1);
        attn_fused_k<<<dim3(NBH, 2), 512, 0, stream>>>(qkvb, tb, nac ? add : nullptr, nac ? DMODEL : 0);
        gemm_mfma2_k<<<dim3(GM, DMODEL / 128, 2), 512, 0, stream>>>(
            tb, wl + WOFF_OUT, out_proj_b + (size_t)l * DMODEL, h, nullptr, ROWS, DMODEL, DMODEL, 3, 0);
        ln768_bf16_k<<<ROWS, 256, 0, stream>>>(h, tb, ln2_w + l * DMODEL, ln2_b + l * DMODEL);
        gemm_mfma2_k<<<dim3(GM, DFF / 128), 512, 0, stream>>>(
            tb, wl + WOFF_FC, fc_b + (size_t)l * DFF, nullptr, gb, ROWS, DFF, DMODEL, 1, 1);
        gemm_mfma2_k<<<dim3(GM, DMODEL / 128, 2), 512, 0, stream>>>(
            gb, wl + WOFF_CP, cproj_b + (size_t)l * DMODEL, h, nullptr, ROWS, DMODEL, DFF, 3, 0);
    }

    ln768_bf16_k<<<ROWS, 256, 0, stream>>>(h, tb, ln_post_w, ln_post_b);
    gemm_mfma_k<<<dim3(GY, DOUT / 128), 256, 0, stream>>>(
        tb, pTs, nullptr, out, nullptr, ROWS, DOUT, DMODEL, 0);
}